// Round 1
// baseline (1012.197 us; speedup 1.0000x reference)
//
#include <hip/hip_runtime.h>
#include <math.h>

#define N_NODES 50000
#define N_EDGES 800000
#define N_GRAPHS 50
#define HD 128
#define TM 64
#define LDA 68
#define POOL_CHUNK 500

// ---------------- degree histograms ----------------
__global__ void k_degrees(const int* __restrict__ src, const int* __restrict__ dst,
                          int* deg_in, int* deg_out) {
    int e = blockIdx.x * blockDim.x + threadIdx.x;
    if (e < N_EDGES) {
        atomicAdd(&deg_in[dst[e]], 1);
        atomicAdd(&deg_out[src[e]], 1);
    }
}

// ---------------- norms + graph counts ----------------
__global__ void k_norms(const int* __restrict__ deg_in, const int* __restrict__ deg_out,
                        const int* __restrict__ gids,
                        float* norm_src, float* norm_dst, int* gcount) {
    int i = blockIdx.x * blockDim.x + threadIdx.x;
    if (i < N_NODES) {
        float di = (float)deg_in[i];
        float dо = (float)deg_out[i];
        norm_dst[i] = 1.0f / sqrtf(fmaxf(di, 1.0f));
        norm_src[i] = 1.0f / sqrtf(fmaxf(dо, 1.0f));
        atomicAdd(&gcount[gids[i]], 1);
    }
}

// ---------------- exclusive scan of in-degrees (single block) ----------------
__global__ void k_scan(const int* __restrict__ deg_in, int* off, int* cursor) {
    __shared__ int sums[1024];
    const int T = 1024;
    const int CH = (N_NODES + T - 1) / T;  // 49
    int t = threadIdx.x;
    int c0 = t * CH;
    int c1 = min(c0 + CH, N_NODES);
    int s = 0;
    for (int i = c0; i < c1; ++i) s += deg_in[i];
    sums[t] = s;
    __syncthreads();
    for (int o = 1; o < T; o <<= 1) {
        int u = (t >= o) ? sums[t - o] : 0;
        __syncthreads();
        sums[t] += u;
        __syncthreads();
    }
    int base = sums[t] - s;  // exclusive prefix
    for (int i = c0; i < c1; ++i) {
        off[i] = base;
        cursor[i] = base;
        base += deg_in[i];
    }
    if (c0 < N_NODES && c1 == N_NODES) off[N_NODES] = base;
}

// ---------------- CSR scatter ----------------
__global__ void k_scatter(const int* __restrict__ src, const int* __restrict__ dst,
                          int* cursor, int* csr) {
    int e = blockIdx.x * blockDim.x + threadIdx.x;
    if (e < N_EDGES) {
        int p = atomicAdd(&cursor[dst[e]], 1);
        csr[p] = src[e];
    }
}

// ---------------- layer-1 aggregation (8-dim features from in-degree) ----------------
__global__ void k_agg1(const int* __restrict__ off, const int* __restrict__ csr,
                       const int* __restrict__ deg_in, const float* __restrict__ nsrc,
                       const float* __restrict__ ndst, float* __restrict__ agg8) {
    int i = blockIdx.x * blockDim.x + threadIdx.x;
    if (i >= N_NODES) return;
    int e0 = off[i], e1 = off[i + 1];
    float a0 = 0.f, a1 = 0.f, a2 = 0.f, a3 = 0.f;
    for (int e = e0; e < e1; ++e) {
        int s = csr[e];
        float ns = nsrc[s];
        float d = (float)deg_in[s];
        a0 += d * ns;
        a1 += (d > 3.0f) ? ns : 0.0f;
        a2 += (3.0f / d) * ns;
        a3 += (d > 4.0f) ? ns : 0.0f;
    }
    float nd = ndst[i];
    a0 *= nd; a1 *= nd; a2 *= nd; a3 *= nd;
    float* p = agg8 + (size_t)i * 8;
    p[0] = a0; p[1] = a1; p[2] = a2; p[3] = a3;
    p[4] = -a0; p[5] = -a1; p[6] = -a2; p[7] = -a3;
}

// ---------------- layer-1 GEMM 8 -> 128, fused bias+relu ----------------
__global__ void k_gemm1(const float* __restrict__ agg8, const float* __restrict__ W,
                        const float* __restrict__ b, float* __restrict__ out) {
    __shared__ float Wsh[8 * 128];
    int t = threadIdx.x;
    for (int i = t; i < 1024; i += 256) Wsh[i] = W[i];
    __syncthreads();
    int row = blockIdx.x * 2 + (t >> 7);
    int j = t & 127;
    if (row >= N_NODES) return;
    const float* a = agg8 + (size_t)row * 8;
    float acc = b[j];
#pragma unroll
    for (int k = 0; k < 8; ++k) acc += a[k] * Wsh[k * 128 + j];
    out[(size_t)row * HD + j] = fmaxf(acc, 0.0f);
}

// ---------------- 128-dim aggregation: one wave per node ----------------
__global__ void k_agg(const int* __restrict__ off, const int* __restrict__ csr,
                      const float* __restrict__ nsrc, const float* __restrict__ ndst,
                      const float* __restrict__ h, float* __restrict__ out) {
    int wid = (blockIdx.x * blockDim.x + threadIdx.x) >> 6;
    int lane = threadIdx.x & 63;
    if (wid >= N_NODES) return;
    int e0 = off[wid], e1 = off[wid + 1];
    float a0 = 0.f, a1 = 0.f;
    int e = e0;
    for (; e + 1 < e1; e += 2) {
        int s0 = csr[e], s1 = csr[e + 1];
        float ns0 = nsrc[s0], ns1 = nsrc[s1];
        float2 v0 = *(const float2*)(h + (size_t)s0 * HD + lane * 2);
        float2 v1 = *(const float2*)(h + (size_t)s1 * HD + lane * 2);
        a0 += v0.x * ns0; a1 += v0.y * ns0;
        a0 += v1.x * ns1; a1 += v1.y * ns1;
    }
    if (e < e1) {
        int s0 = csr[e];
        float ns0 = nsrc[s0];
        float2 v0 = *(const float2*)(h + (size_t)s0 * HD + lane * 2);
        a0 += v0.x * ns0; a1 += v0.y * ns0;
    }
    float nd = ndst[wid];
    float2 o; o.x = a0 * nd; o.y = a1 * nd;
    *(float2*)(out + (size_t)wid * HD + lane * 2) = o;
}

// ---------------- 128x128 GEMM, W + A^T in LDS, fused bias+relu ----------------
__global__ __launch_bounds__(512) void k_gemm(const float* __restrict__ A,
                                              const float* __restrict__ W,
                                              const float* __restrict__ b,
                                              float* __restrict__ out) {
    __shared__ float Wsh[128 * 128];      // 64 KB
    __shared__ float Ash[128 * LDA];      // ~34 KB, transposed A tile
    int t = threadIdx.x;
    const float4* W4 = (const float4*)W;
    float4* Wsh4 = (float4*)Wsh;
#pragma unroll
    for (int i = 0; i < 8; ++i) Wsh4[t + i * 512] = W4[t + i * 512];
    int row0 = blockIdx.x * TM;
#pragma unroll
    for (int i = 0; i < 4; ++i) {
        int idx = t + i * 512;      // 0..2047 float4 index over 64x128 tile
        int r = idx >> 5;           // row within tile
        int q = idx & 31;           // float4 column
        int row = row0 + r;
        if (row >= N_NODES) row = N_NODES - 1;
        float4 v = ((const float4*)(A + (size_t)row * HD))[q];
        Ash[(4 * q + 0) * LDA + r] = v.x;
        Ash[(4 * q + 1) * LDA + r] = v.y;
        Ash[(4 * q + 2) * LDA + r] = v.z;
        Ash[(4 * q + 3) * LDA + r] = v.w;
    }
    __syncthreads();
    int j0 = (t & 31) * 4;
    int r0 = (t >> 5) * 4;
    float4 bv = *(const float4*)(b + j0);
    float acc[4][4];
#pragma unroll
    for (int r = 0; r < 4; ++r) {
        acc[r][0] = bv.x; acc[r][1] = bv.y; acc[r][2] = bv.z; acc[r][3] = bv.w;
    }
#pragma unroll 4
    for (int k = 0; k < 128; ++k) {
        float4 w = *(const float4*)&Wsh[k * 128 + j0];
        float4 a = *(const float4*)&Ash[k * LDA + r0];
        acc[0][0] += a.x * w.x; acc[0][1] += a.x * w.y; acc[0][2] += a.x * w.z; acc[0][3] += a.x * w.w;
        acc[1][0] += a.y * w.x; acc[1][1] += a.y * w.y; acc[1][2] += a.y * w.z; acc[1][3] += a.y * w.w;
        acc[2][0] += a.z * w.x; acc[2][1] += a.z * w.y; acc[2][2] += a.z * w.z; acc[2][3] += a.z * w.w;
        acc[3][0] += a.w * w.x; acc[3][1] += a.w * w.y; acc[3][2] += a.w * w.z; acc[3][3] += a.w * w.w;
    }
#pragma unroll
    for (int r = 0; r < 4; ++r) {
        int row = row0 + r0 + r;
        if (row < N_NODES) {
            float* op = out + (size_t)row * HD + j0;
            float2 o01 = { fmaxf(acc[r][0], 0.f), fmaxf(acc[r][1], 0.f) };
            float2 o23 = { fmaxf(acc[r][2], 0.f), fmaxf(acc[r][3], 0.f) };
            *(float2*)op = o01;              // out may be only 8B-aligned (d_out+6450 floats)
            *(float2*)(op + 2) = o23;
        }
    }
}

// ---------------- mean-pool partials (500-node chunks, uniform graph id) ----------------
__global__ void k_pool(const float* __restrict__ hco, const int* __restrict__ gids,
                       float* gsum) {
    int f = threadIdx.x;                 // 128
    int n0 = blockIdx.x * POOL_CHUNK;
    int g = gids[n0];
    float s = 0.f;
    for (int i = 0; i < POOL_CHUNK; ++i)
        s += hco[(size_t)(n0 + i) * HD + f];
    atomicAdd(&gsum[g * HD + f], s);
}

// ---------------- head: graph_emb, MLP, sigmoid ----------------
__global__ void k_head(const float* __restrict__ gsum, const int* __restrict__ gcount,
                       const float* __restrict__ lw1, const float* __restrict__ lb1,
                       const float* __restrict__ lw2, const float* __restrict__ lb2,
                       float* __restrict__ dout) {
    __shared__ float ge[128];
    int g = blockIdx.x, j = threadIdx.x;  // 64 threads
    float cnt = (float)gcount[g];
    float g0 = gsum[g * HD + j] / cnt;
    float g1 = gsum[g * HD + 64 + j] / cnt;
    ge[j] = g0; ge[64 + j] = g1;
    dout[N_GRAPHS + g * HD + j] = g0;
    dout[N_GRAPHS + g * HD + 64 + j] = g1;
    __syncthreads();
    float acc = lb1[j];
#pragma unroll 4
    for (int k = 0; k < 128; ++k) acc += ge[k] * lw1[k * 64 + j];
    float he = fmaxf(acc, 0.f);
    float p = he * lw2[j];
#pragma unroll
    for (int o = 32; o > 0; o >>= 1) p += __shfl_down(p, o);
    if (j == 0) dout[g] = 1.0f / (1.0f + expf(-(p + lb2[0])));
}

extern "C" void kernel_launch(void* const* d_in, const int* in_sizes, int n_in,
                              void* d_out, int out_size, void* d_ws, size_t ws_size,
                              hipStream_t stream) {
    const int* src  = (const int*)d_in[0];
    const int* dst  = (const int*)d_in[1];
    const int* gids = (const int*)d_in[2];
    const float* W1 = (const float*)d_in[3];  const float* b1 = (const float*)d_in[4];
    const float* W2 = (const float*)d_in[5];  const float* b2 = (const float*)d_in[6];
    const float* W3 = (const float*)d_in[7];  const float* b3 = (const float*)d_in[8];
    const float* W4 = (const float*)d_in[9];  const float* b4 = (const float*)d_in[10];
    const float* W5 = (const float*)d_in[11]; const float* b5 = (const float*)d_in[12];
    const float* lw1 = (const float*)d_in[13]; const float* lb1 = (const float*)d_in[14];
    const float* lw2 = (const float*)d_in[15]; const float* lb2 = (const float*)d_in[16];
    float* out = (float*)d_out;

    char* ws = (char*)d_ws;
    // workspace layout (256B-aligned chunks)
    int*   deg_in   = (int*)(ws + 0);              // 200192 B
    int*   deg_out  = (int*)(ws + 200192);         // 200192 B
    int*   gcount   = (int*)(ws + 400384);         // 256 B
    float* gsum     = (float*)(ws + 400640);       // 25600 B
    const size_t ZERO_BYTES = 426240;              // everything above gets zeroed
    int*   off      = (int*)(ws + 426240);         // 200192 B
    int*   cursor   = (int*)(ws + 626432);         // 200192 B
    int*   csr      = (int*)(ws + 826624);         // 3200000 B
    float* norm_src = (float*)(ws + 4026624);      // 200192 B
    float* norm_dst = (float*)(ws + 4226816);      // 200192 B
    float* aggbuf   = (float*)(ws + 4427008);      // 25.6 MB (also holds agg8 for layer 1)

    float* hbuf = out + (N_GRAPHS + N_GRAPHS * HD);  // h lives in d_out's h_co region

    hipMemsetAsync(ws, 0, ZERO_BYTES, stream);

    k_degrees<<<(N_EDGES + 255) / 256, 256, 0, stream>>>(src, dst, deg_in, deg_out);
    k_norms<<<(N_NODES + 255) / 256, 256, 0, stream>>>(deg_in, deg_out, gids,
                                                       norm_src, norm_dst, gcount);
    k_scan<<<1, 1024, 0, stream>>>(deg_in, off, cursor);
    k_scatter<<<(N_EDGES + 255) / 256, 256, 0, stream>>>(src, dst, cursor, csr);

    // layer 1: 8-dim features -> 128
    k_agg1<<<(N_NODES + 255) / 256, 256, 0, stream>>>(off, csr, deg_in, norm_src,
                                                      norm_dst, aggbuf);
    k_gemm1<<<N_NODES / 2, 256, 0, stream>>>(aggbuf, W1, b1, hbuf);

    // layers 2..5
    const float* Ws[4] = { W2, W3, W4, W5 };
    const float* bs[4] = { b2, b3, b4, b5 };
    for (int L = 0; L < 4; ++L) {
        k_agg<<<(N_NODES * 64 + 255) / 256, 256, 0, stream>>>(off, csr, norm_src,
                                                              norm_dst, hbuf, aggbuf);
        k_gemm<<<(N_NODES + TM - 1) / TM, 512, 0, stream>>>(aggbuf, Ws[L], bs[L], hbuf);
    }

    // pooling + head
    k_pool<<<N_NODES / POOL_CHUNK, 128, 0, stream>>>(hbuf, gids, gsum);
    k_head<<<N_GRAPHS, 64, 0, stream>>>(gsum, gcount, lw1, lb1, lw2, lb2, out);
}

// Round 2
// 764.292 us; speedup vs baseline: 1.3244x; 1.3244x over previous
//
#include <hip/hip_runtime.h>
#include <math.h>

#define N_NODES 50000
#define N_EDGES 800000
#define N_GRAPHS 50
#define HD 128
#define TM 64
#define LDA 68
#define POOL_CHUNK 125

// ---------------- degree histograms ----------------
__global__ void k_degrees(const int* __restrict__ src, const int* __restrict__ dst,
                          int* deg_in, int* deg_out) {
    int e = blockIdx.x * blockDim.x + threadIdx.x;
    if (e < N_EDGES) {
        atomicAdd(&deg_in[dst[e]], 1);
        atomicAdd(&deg_out[src[e]], 1);
    }
}

// ---------------- norms + graph counts (LDS histogram to kill same-address atomics) ----
__global__ void k_norms(const int* __restrict__ deg_in, const int* __restrict__ deg_out,
                        const int* __restrict__ gids,
                        float* norm_src, float* norm_dst, int* gcount) {
    __shared__ int hist[N_GRAPHS];
    int t = threadIdx.x;
    if (t < N_GRAPHS) hist[t] = 0;
    __syncthreads();
    int i = blockIdx.x * blockDim.x + t;
    if (i < N_NODES) {
        float di = (float)deg_in[i];
        float dq = (float)deg_out[i];
        norm_dst[i] = 1.0f / sqrtf(fmaxf(di, 1.0f));
        norm_src[i] = 1.0f / sqrtf(fmaxf(dq, 1.0f));
        atomicAdd(&hist[gids[i]], 1);
    }
    __syncthreads();
    if (t < N_GRAPHS && hist[t] != 0) atomicAdd(&gcount[t], hist[t]);
}

// ---------------- exclusive scan of in-degrees (single block) ----------------
__global__ void k_scan(const int* __restrict__ deg_in, int* off, int* cursor) {
    __shared__ int sums[1024];
    const int T = 1024;
    const int CH = (N_NODES + T - 1) / T;  // 49
    int t = threadIdx.x;
    int c0 = t * CH;
    int c1 = min(c0 + CH, N_NODES);
    int s = 0;
    for (int i = c0; i < c1; ++i) s += deg_in[i];
    sums[t] = s;
    __syncthreads();
    for (int o = 1; o < T; o <<= 1) {
        int u = (t >= o) ? sums[t - o] : 0;
        __syncthreads();
        sums[t] += u;
        __syncthreads();
    }
    int base = sums[t] - s;  // exclusive prefix
    for (int i = c0; i < c1; ++i) {
        off[i] = base;
        cursor[i] = base;
        base += deg_in[i];
    }
    if (c0 < N_NODES && c1 == N_NODES) off[N_NODES] = base;
}

// ---------------- CSR scatter ----------------
__global__ void k_scatter(const int* __restrict__ src, const int* __restrict__ dst,
                          int* cursor, int* csr) {
    int e = blockIdx.x * blockDim.x + threadIdx.x;
    if (e < N_EDGES) {
        int p = atomicAdd(&cursor[dst[e]], 1);
        csr[p] = src[e];
    }
}

// ---------------- layer-1 aggregation (8-dim features from in-degree) ----------------
__global__ void k_agg1(const int* __restrict__ off, const int* __restrict__ csr,
                       const int* __restrict__ deg_in, const float* __restrict__ nsrc,
                       const float* __restrict__ ndst, float* __restrict__ agg8) {
    int i = blockIdx.x * blockDim.x + threadIdx.x;
    if (i >= N_NODES) return;
    int e0 = off[i], e1 = off[i + 1];
    float a0 = 0.f, a1 = 0.f, a2 = 0.f, a3 = 0.f;
    for (int e = e0; e < e1; ++e) {
        int s = csr[e];
        float ns = nsrc[s];
        float d = (float)deg_in[s];
        a0 += d * ns;
        a1 += (d > 3.0f) ? ns : 0.0f;
        a2 += (3.0f / d) * ns;
        a3 += (d > 4.0f) ? ns : 0.0f;
    }
    float nd = ndst[i];
    a0 *= nd; a1 *= nd; a2 *= nd; a3 *= nd;
    float* p = agg8 + (size_t)i * 8;
    p[0] = a0; p[1] = a1; p[2] = a2; p[3] = a3;
    p[4] = -a0; p[5] = -a1; p[6] = -a2; p[7] = -a3;
}

// ---------------- layer-1 GEMM 8 -> 128, fused bias+relu ----------------
__global__ void k_gemm1(const float* __restrict__ agg8, const float* __restrict__ W,
                        const float* __restrict__ b, float* __restrict__ out) {
    __shared__ float Wsh[8 * 128];
    int t = threadIdx.x;
    for (int i = t; i < 1024; i += 256) Wsh[i] = W[i];
    __syncthreads();
    int row = blockIdx.x * 2 + (t >> 7);
    int j = t & 127;
    if (row >= N_NODES) return;
    const float* a = agg8 + (size_t)row * 8;
    float acc = b[j];
#pragma unroll
    for (int k = 0; k < 8; ++k) acc += a[k] * Wsh[k * 128 + j];
    out[(size_t)row * HD + j] = fmaxf(acc, 0.0f);
}

// ---------------- 128-dim aggregation: one wave per node ----------------
__global__ void k_agg(const int* __restrict__ off, const int* __restrict__ csr,
                      const float* __restrict__ nsrc, const float* __restrict__ ndst,
                      const float* __restrict__ h, float* __restrict__ out) {
    int wid = (blockIdx.x * blockDim.x + threadIdx.x) >> 6;
    int lane = threadIdx.x & 63;
    if (wid >= N_NODES) return;
    int e0 = off[wid], e1 = off[wid + 1];
    float a0 = 0.f, a1 = 0.f;
    int e = e0;
    for (; e + 1 < e1; e += 2) {
        int s0 = csr[e], s1 = csr[e + 1];
        float ns0 = nsrc[s0], ns1 = nsrc[s1];
        float2 v0 = *(const float2*)(h + (size_t)s0 * HD + lane * 2);
        float2 v1 = *(const float2*)(h + (size_t)s1 * HD + lane * 2);
        a0 += v0.x * ns0; a1 += v0.y * ns0;
        a0 += v1.x * ns1; a1 += v1.y * ns1;
    }
    if (e < e1) {
        int s0 = csr[e];
        float ns0 = nsrc[s0];
        float2 v0 = *(const float2*)(h + (size_t)s0 * HD + lane * 2);
        a0 += v0.x * ns0; a1 += v0.y * ns0;
    }
    float nd = ndst[wid];
    float2 o; o.x = a0 * nd; o.y = a1 * nd;
    *(float2*)(out + (size_t)wid * HD + lane * 2) = o;
}

// ---------------- 128x128 GEMM, W + A^T in LDS, fused bias+relu ----------------
__global__ __launch_bounds__(512) void k_gemm(const float* __restrict__ A,
                                              const float* __restrict__ W,
                                              const float* __restrict__ b,
                                              float* __restrict__ out) {
    __shared__ float Wsh[128 * 128];      // 64 KB
    __shared__ float Ash[128 * LDA];      // ~34 KB, transposed A tile
    int t = threadIdx.x;
    const float4* W4 = (const float4*)W;
    float4* Wsh4 = (float4*)Wsh;
#pragma unroll
    for (int i = 0; i < 8; ++i) Wsh4[t + i * 512] = W4[t + i * 512];
    int row0 = blockIdx.x * TM;
#pragma unroll
    for (int i = 0; i < 4; ++i) {
        int idx = t + i * 512;      // 0..2047 float4 index over 64x128 tile
        int r = idx >> 5;           // row within tile
        int q = idx & 31;           // float4 column
        int row = row0 + r;
        if (row >= N_NODES) row = N_NODES - 1;
        float4 v = ((const float4*)(A + (size_t)row * HD))[q];
        Ash[(4 * q + 0) * LDA + r] = v.x;
        Ash[(4 * q + 1) * LDA + r] = v.y;
        Ash[(4 * q + 2) * LDA + r] = v.z;
        Ash[(4 * q + 3) * LDA + r] = v.w;
    }
    __syncthreads();
    int j0 = (t & 31) * 4;
    int r0 = (t >> 5) * 4;
    float4 bv = *(const float4*)(b + j0);
    float acc[4][4];
#pragma unroll
    for (int r = 0; r < 4; ++r) {
        acc[r][0] = bv.x; acc[r][1] = bv.y; acc[r][2] = bv.z; acc[r][3] = bv.w;
    }
#pragma unroll 4
    for (int k = 0; k < 128; ++k) {
        float4 w = *(const float4*)&Wsh[k * 128 + j0];
        float4 a = *(const float4*)&Ash[k * LDA + r0];
        acc[0][0] += a.x * w.x; acc[0][1] += a.x * w.y; acc[0][2] += a.x * w.z; acc[0][3] += a.x * w.w;
        acc[1][0] += a.y * w.x; acc[1][1] += a.y * w.y; acc[1][2] += a.y * w.z; acc[1][3] += a.y * w.w;
        acc[2][0] += a.z * w.x; acc[2][1] += a.z * w.y; acc[2][2] += a.z * w.z; acc[2][3] += a.z * w.w;
        acc[3][0] += a.w * w.x; acc[3][1] += a.w * w.y; acc[3][2] += a.w * w.z; acc[3][3] += a.w * w.w;
    }
#pragma unroll
    for (int r = 0; r < 4; ++r) {
        int row = row0 + r0 + r;
        if (row < N_NODES) {
            float* op = out + (size_t)row * HD + j0;
            float2 o01 = { fmaxf(acc[r][0], 0.f), fmaxf(acc[r][1], 0.f) };
            float2 o23 = { fmaxf(acc[r][2], 0.f), fmaxf(acc[r][3], 0.f) };
            *(float2*)op = o01;              // out may be only 8B-aligned (d_out+6450 floats)
            *(float2*)(op + 2) = o23;
        }
    }
}

// ---------------- mean-pool partials (125-node chunks, uniform graph id) ----------------
__global__ void k_pool(const float* __restrict__ hco, const int* __restrict__ gids,
                       float* gsum) {
    int f = threadIdx.x;                 // 128
    int n0 = blockIdx.x * POOL_CHUNK;
    int g = gids[n0];
    float s = 0.f;
    for (int i = 0; i < POOL_CHUNK; ++i)
        s += hco[(size_t)(n0 + i) * HD + f];
    atomicAdd(&gsum[g * HD + f], s);
}

// ---------------- head: graph_emb, MLP, sigmoid ----------------
__global__ void k_head(const float* __restrict__ gsum, const int* __restrict__ gcount,
                       const float* __restrict__ lw1, const float* __restrict__ lb1,
                       const float* __restrict__ lw2, const float* __restrict__ lb2,
                       float* __restrict__ dout) {
    __shared__ float ge[128];
    int g = blockIdx.x, j = threadIdx.x;  // 64 threads
    float cnt = (float)gcount[g];
    float g0 = gsum[g * HD + j] / cnt;
    float g1 = gsum[g * HD + 64 + j] / cnt;
    ge[j] = g0; ge[64 + j] = g1;
    dout[N_GRAPHS + g * HD + j] = g0;
    dout[N_GRAPHS + g * HD + 64 + j] = g1;
    __syncthreads();
    float acc = lb1[j];
#pragma unroll 4
    for (int k = 0; k < 128; ++k) acc += ge[k] * lw1[k * 64 + j];
    float he = fmaxf(acc, 0.f);
    float p = he * lw2[j];
#pragma unroll
    for (int o = 32; o > 0; o >>= 1) p += __shfl_down(p, o);
    if (j == 0) dout[g] = 1.0f / (1.0f + expf(-(p + lb2[0])));
}

extern "C" void kernel_launch(void* const* d_in, const int* in_sizes, int n_in,
                              void* d_out, int out_size, void* d_ws, size_t ws_size,
                              hipStream_t stream) {
    const int* src  = (const int*)d_in[0];
    const int* dst  = (const int*)d_in[1];
    const int* gids = (const int*)d_in[2];
    const float* W1 = (const float*)d_in[3];  const float* b1 = (const float*)d_in[4];
    const float* W2 = (const float*)d_in[5];  const float* b2 = (const float*)d_in[6];
    const float* W3 = (const float*)d_in[7];  const float* b3 = (const float*)d_in[8];
    const float* W4 = (const float*)d_in[9];  const float* b4 = (const float*)d_in[10];
    const float* W5 = (const float*)d_in[11]; const float* b5 = (const float*)d_in[12];
    const float* lw1 = (const float*)d_in[13]; const float* lb1 = (const float*)d_in[14];
    const float* lw2 = (const float*)d_in[15]; const float* lb2 = (const float*)d_in[16];
    float* out = (float*)d_out;

    char* ws = (char*)d_ws;
    // workspace layout (256B-aligned chunks)
    int*   deg_in   = (int*)(ws + 0);              // 200192 B
    int*   deg_out  = (int*)(ws + 200192);         // 200192 B
    int*   gcount   = (int*)(ws + 400384);         // 256 B
    float* gsum     = (float*)(ws + 400640);       // 25600 B
    const size_t ZERO_BYTES = 426240;              // everything above gets zeroed
    int*   off      = (int*)(ws + 426240);         // 200192 B
    int*   cursor   = (int*)(ws + 626432);         // 200192 B
    int*   csr      = (int*)(ws + 826624);         // 3200000 B
    float* norm_src = (float*)(ws + 4026624);      // 200192 B
    float* norm_dst = (float*)(ws + 4226816);      // 200192 B
    float* aggbuf   = (float*)(ws + 4427008);      // 25.6 MB (also holds agg8 for layer 1)

    float* hbuf = out + (N_GRAPHS + N_GRAPHS * HD);  // h lives in d_out's h_co region

    hipMemsetAsync(ws, 0, ZERO_BYTES, stream);

    k_degrees<<<(N_EDGES + 255) / 256, 256, 0, stream>>>(src, dst, deg_in, deg_out);
    k_norms<<<(N_NODES + 255) / 256, 256, 0, stream>>>(deg_in, deg_out, gids,
                                                       norm_src, norm_dst, gcount);
    k_scan<<<1, 1024, 0, stream>>>(deg_in, off, cursor);
    k_scatter<<<(N_EDGES + 255) / 256, 256, 0, stream>>>(src, dst, cursor, csr);

    // layer 1: 8-dim features -> 128
    k_agg1<<<(N_NODES + 255) / 256, 256, 0, stream>>>(off, csr, deg_in, norm_src,
                                                      norm_dst, aggbuf);
    k_gemm1<<<N_NODES / 2, 256, 0, stream>>>(aggbuf, W1, b1, hbuf);

    // layers 2..5
    const float* Ws[4] = { W2, W3, W4, W5 };
    const float* bs[4] = { b2, b3, b4, b5 };
    for (int L = 0; L < 4; ++L) {
        k_agg<<<(N_NODES * 64 + 255) / 256, 256, 0, stream>>>(off, csr, norm_src,
                                                              norm_dst, hbuf, aggbuf);
        k_gemm<<<(N_NODES + TM - 1) / TM, 512, 0, stream>>>(aggbuf, Ws[L], bs[L], hbuf);
    }

    // pooling + head
    k_pool<<<N_NODES / POOL_CHUNK, 128, 0, stream>>>(hbuf, gids, gsum);
    k_head<<<N_GRAPHS, 64, 0, stream>>>(gsum, gcount, lw1, lb1, lw2, lb2, out);
}

// Round 3
// 664.719 us; speedup vs baseline: 1.5227x; 1.1498x over previous
//
#include <hip/hip_runtime.h>
#include <math.h>

#define N_NODES 50000
#define N_EDGES 800000
#define N_GRAPHS 50
#define HD 128
#define TM 64
#define LDA 68
#define POOL_CHUNK 125
#define SCAN_B 256
#define SCAN_NB ((N_NODES + SCAN_B - 1) / SCAN_B)   // 196

// ---------------- degree histograms ----------------
__global__ void k_degrees(const int* __restrict__ src, const int* __restrict__ dst,
                          int* deg_in, int* deg_out) {
    int e = blockIdx.x * blockDim.x + threadIdx.x;
    if (e < N_EDGES) {
        atomicAdd(&deg_in[dst[e]], 1);
        atomicAdd(&deg_out[src[e]], 1);
    }
}

// ---------------- norms + graph counts (LDS histogram) ----------------
__global__ void k_norms(const int* __restrict__ deg_in, const int* __restrict__ deg_out,
                        const int* __restrict__ gids,
                        float* norm_src, float* norm_dst, int* gcount) {
    __shared__ int hist[N_GRAPHS];
    int t = threadIdx.x;
    if (t < N_GRAPHS) hist[t] = 0;
    __syncthreads();
    int i = blockIdx.x * blockDim.x + t;
    if (i < N_NODES) {
        float di = (float)deg_in[i];
        float dq = (float)deg_out[i];
        norm_dst[i] = 1.0f / sqrtf(fmaxf(di, 1.0f));
        norm_src[i] = 1.0f / sqrtf(fmaxf(dq, 1.0f));
        atomicAdd(&hist[gids[i]], 1);
    }
    __syncthreads();
    if (t < N_GRAPHS && hist[t] != 0) atomicAdd(&gcount[t], hist[t]);
}

// ---------------- device-wide exclusive scan, 3 phases ----------------
__global__ void k_scan1(const int* __restrict__ deg_in, int* off, int* bsum) {
    __shared__ int sh[SCAN_B];
    int t = threadIdx.x;
    int i = blockIdx.x * SCAN_B + t;
    int v = (i < N_NODES) ? deg_in[i] : 0;
    sh[t] = v;
    __syncthreads();
    for (int o = 1; o < SCAN_B; o <<= 1) {
        int u = (t >= o) ? sh[t - o] : 0;
        __syncthreads();
        sh[t] += u;
        __syncthreads();
    }
    if (i < N_NODES) off[i] = sh[t] - v;          // local exclusive prefix
    if (t == SCAN_B - 1) bsum[blockIdx.x] = sh[t]; // block total
}

__global__ void k_scan2(int* bsum, int* off) {
    __shared__ int sh[SCAN_B];
    int t = threadIdx.x;
    int v = (t < SCAN_NB) ? bsum[t] : 0;
    sh[t] = v;
    __syncthreads();
    for (int o = 1; o < SCAN_B; o <<= 1) {
        int u = (t >= o) ? sh[t - o] : 0;
        __syncthreads();
        sh[t] += u;
        __syncthreads();
    }
    if (t < SCAN_NB) bsum[t] = sh[t] - v;          // exclusive block base
    if (t == SCAN_B - 1) off[N_NODES] = sh[t];     // total (= E)
}

__global__ void k_scan3(int* off, const int* __restrict__ bsum, int* cursor) {
    int b = blockIdx.x, t = threadIdx.x;
    int i = b * SCAN_B + t;
    if (i < N_NODES) {
        int o = off[i] + bsum[b];
        off[i] = o;
        cursor[i] = o;
    }
}

// ---------------- CSR scatter ----------------
__global__ void k_scatter(const int* __restrict__ src, const int* __restrict__ dst,
                          int* cursor, int* csr) {
    int e = blockIdx.x * blockDim.x + threadIdx.x;
    if (e < N_EDGES) {
        int p = atomicAdd(&cursor[dst[e]], 1);
        csr[p] = src[e];
    }
}

// ---------------- layer-1 aggregation (8-dim features from in-degree) ----------------
__global__ void k_agg1(const int* __restrict__ off, const int* __restrict__ csr,
                       const int* __restrict__ deg_in, const float* __restrict__ nsrc,
                       const float* __restrict__ ndst, float* __restrict__ agg8) {
    int i = blockIdx.x * blockDim.x + threadIdx.x;
    if (i >= N_NODES) return;
    int e0 = off[i], e1 = off[i + 1];
    float a0 = 0.f, a1 = 0.f, a2 = 0.f, a3 = 0.f;
    for (int e = e0; e < e1; ++e) {
        int s = csr[e];
        float ns = nsrc[s];
        float d = (float)deg_in[s];
        a0 += d * ns;
        a1 += (d > 3.0f) ? ns : 0.0f;
        a2 += (3.0f / d) * ns;
        a3 += (d > 4.0f) ? ns : 0.0f;
    }
    float nd = ndst[i];
    a0 *= nd; a1 *= nd; a2 *= nd; a3 *= nd;
    float* p = agg8 + (size_t)i * 8;
    p[0] = a0; p[1] = a1; p[2] = a2; p[3] = a3;
    p[4] = -a0; p[5] = -a1; p[6] = -a2; p[7] = -a3;
}

// ---------------- layer-1 GEMM 8 -> 128, fused bias+relu ----------------
__global__ void k_gemm1(const float* __restrict__ agg8, const float* __restrict__ W,
                        const float* __restrict__ b, float* __restrict__ out) {
    __shared__ float Wsh[8 * 128];
    int t = threadIdx.x;
    for (int i = t; i < 1024; i += 256) Wsh[i] = W[i];
    __syncthreads();
    int row = blockIdx.x * 2 + (t >> 7);
    int j = t & 127;
    if (row >= N_NODES) return;
    const float* a = agg8 + (size_t)row * 8;
    float acc = b[j];
#pragma unroll
    for (int k = 0; k < 8; ++k) acc += a[k] * Wsh[k * 128 + j];
    out[(size_t)row * HD + j] = fmaxf(acc, 0.0f);
}

// ---------------- 128-dim aggregation: one wave per node ----------------
__global__ void k_agg(const int* __restrict__ off, const int* __restrict__ csr,
                      const float* __restrict__ nsrc, const float* __restrict__ ndst,
                      const float* __restrict__ h, float* __restrict__ out) {
    int wid = (blockIdx.x * blockDim.x + threadIdx.x) >> 6;
    int lane = threadIdx.x & 63;
    if (wid >= N_NODES) return;
    int e0 = off[wid], e1 = off[wid + 1];
    float a0 = 0.f, a1 = 0.f;
    int e = e0;
    for (; e + 1 < e1; e += 2) {
        int s0 = csr[e], s1 = csr[e + 1];
        float ns0 = nsrc[s0], ns1 = nsrc[s1];
        float2 v0 = *(const float2*)(h + (size_t)s0 * HD + lane * 2);
        float2 v1 = *(const float2*)(h + (size_t)s1 * HD + lane * 2);
        a0 += v0.x * ns0; a1 += v0.y * ns0;
        a0 += v1.x * ns1; a1 += v1.y * ns1;
    }
    if (e < e1) {
        int s0 = csr[e];
        float ns0 = nsrc[s0];
        float2 v0 = *(const float2*)(h + (size_t)s0 * HD + lane * 2);
        a0 += v0.x * ns0; a1 += v0.y * ns0;
    }
    float nd = ndst[wid];
    float2 o; o.x = a0 * nd; o.y = a1 * nd;
    *(float2*)(out + (size_t)wid * HD + lane * 2) = o;
}

// ---------------- 128x128 GEMM, W + A^T in LDS, fused bias+relu ----------------
__global__ __launch_bounds__(512) void k_gemm(const float* __restrict__ A,
                                              const float* __restrict__ W,
                                              const float* __restrict__ b,
                                              float* __restrict__ out) {
    __shared__ float Wsh[128 * 128];      // 64 KB
    __shared__ float Ash[128 * LDA];      // ~34 KB, transposed A tile
    int t = threadIdx.x;
    const float4* W4 = (const float4*)W;
    float4* Wsh4 = (float4*)Wsh;
#pragma unroll
    for (int i = 0; i < 8; ++i) Wsh4[t + i * 512] = W4[t + i * 512];
    int row0 = blockIdx.x * TM;
#pragma unroll
    for (int i = 0; i < 4; ++i) {
        int idx = t + i * 512;      // 0..2047 float4 index over 64x128 tile
        int r = idx >> 5;           // row within tile
        int q = idx & 31;           // float4 column
        int row = row0 + r;
        if (row >= N_NODES) row = N_NODES - 1;
        float4 v = ((const float4*)(A + (size_t)row * HD))[q];
        Ash[(4 * q + 0) * LDA + r] = v.x;
        Ash[(4 * q + 1) * LDA + r] = v.y;
        Ash[(4 * q + 2) * LDA + r] = v.z;
        Ash[(4 * q + 3) * LDA + r] = v.w;
    }
    __syncthreads();
    int j0 = (t & 31) * 4;
    int r0 = (t >> 5) * 4;
    float4 bv = *(const float4*)(b + j0);
    float acc[4][4];
#pragma unroll
    for (int r = 0; r < 4; ++r) {
        acc[r][0] = bv.x; acc[r][1] = bv.y; acc[r][2] = bv.z; acc[r][3] = bv.w;
    }
#pragma unroll 4
    for (int k = 0; k < 128; ++k) {
        float4 w = *(const float4*)&Wsh[k * 128 + j0];
        float4 a = *(const float4*)&Ash[k * LDA + r0];
        acc[0][0] += a.x * w.x; acc[0][1] += a.x * w.y; acc[0][2] += a.x * w.z; acc[0][3] += a.x * w.w;
        acc[1][0] += a.y * w.x; acc[1][1] += a.y * w.y; acc[1][2] += a.y * w.z; acc[1][3] += a.y * w.w;
        acc[2][0] += a.z * w.x; acc[2][1] += a.z * w.y; acc[2][2] += a.z * w.z; acc[2][3] += a.z * w.w;
        acc[3][0] += a.w * w.x; acc[3][1] += a.w * w.y; acc[3][2] += a.w * w.z; acc[3][3] += a.w * w.w;
    }
#pragma unroll
    for (int r = 0; r < 4; ++r) {
        int row = row0 + r0 + r;
        if (row < N_NODES) {
            float* op = out + (size_t)row * HD + j0;
            float2 o01 = { fmaxf(acc[r][0], 0.f), fmaxf(acc[r][1], 0.f) };
            float2 o23 = { fmaxf(acc[r][2], 0.f), fmaxf(acc[r][3], 0.f) };
            *(float2*)op = o01;              // out may be only 8B-aligned (d_out+6450 floats)
            *(float2*)(op + 2) = o23;
        }
    }
}

// ---------------- mean-pool partials (125-node chunks, uniform graph id) ----------------
__global__ void k_pool(const float* __restrict__ hco, const int* __restrict__ gids,
                       float* gsum) {
    int f = threadIdx.x;                 // 128
    int n0 = blockIdx.x * POOL_CHUNK;
    int g = gids[n0];
    float s = 0.f;
    for (int i = 0; i < POOL_CHUNK; ++i)
        s += hco[(size_t)(n0 + i) * HD + f];
    atomicAdd(&gsum[g * HD + f], s);
}

// ---------------- head: graph_emb, MLP, sigmoid ----------------
__global__ void k_head(const float* __restrict__ gsum, const int* __restrict__ gcount,
                       const float* __restrict__ lw1, const float* __restrict__ lb1,
                       const float* __restrict__ lw2, const float* __restrict__ lb2,
                       float* __restrict__ dout) {
    __shared__ float ge[128];
    int g = blockIdx.x, j = threadIdx.x;  // 64 threads
    float cnt = (float)gcount[g];
    float g0 = gsum[g * HD + j] / cnt;
    float g1 = gsum[g * HD + 64 + j] / cnt;
    ge[j] = g0; ge[64 + j] = g1;
    dout[N_GRAPHS + g * HD + j] = g0;
    dout[N_GRAPHS + g * HD + 64 + j] = g1;
    __syncthreads();
    float acc = lb1[j];
#pragma unroll 4
    for (int k = 0; k < 128; ++k) acc += ge[k] * lw1[k * 64 + j];
    float he = fmaxf(acc, 0.f);
    float p = he * lw2[j];
#pragma unroll
    for (int o = 32; o > 0; o >>= 1) p += __shfl_down(p, o);
    if (j == 0) dout[g] = 1.0f / (1.0f + expf(-(p + lb2[0])));
}

extern "C" void kernel_launch(void* const* d_in, const int* in_sizes, int n_in,
                              void* d_out, int out_size, void* d_ws, size_t ws_size,
                              hipStream_t stream) {
    const int* src  = (const int*)d_in[0];
    const int* dst  = (const int*)d_in[1];
    const int* gids = (const int*)d_in[2];
    const float* W1 = (const float*)d_in[3];  const float* b1 = (const float*)d_in[4];
    const float* W2 = (const float*)d_in[5];  const float* b2 = (const float*)d_in[6];
    const float* W3 = (const float*)d_in[7];  const float* b3 = (const float*)d_in[8];
    const float* W4 = (const float*)d_in[9];  const float* b4 = (const float*)d_in[10];
    const float* W5 = (const float*)d_in[11]; const float* b5 = (const float*)d_in[12];
    const float* lw1 = (const float*)d_in[13]; const float* lb1 = (const float*)d_in[14];
    const float* lw2 = (const float*)d_in[15]; const float* lb2 = (const float*)d_in[16];
    float* out = (float*)d_out;

    char* ws = (char*)d_ws;
    // workspace layout (256B-aligned chunks)
    int*   deg_in   = (int*)(ws + 0);              // 200192 B
    int*   deg_out  = (int*)(ws + 200192);         // 200192 B
    int*   gcount   = (int*)(ws + 400384);         // 256 B
    float* gsum     = (float*)(ws + 400640);       // 25600 B
    const size_t ZERO_BYTES = 426240;              // everything above gets zeroed
    int*   off      = (int*)(ws + 426240);         // 200192 B
    int*   cursor   = (int*)(ws + 626432);         // 200192 B
    int*   csr      = (int*)(ws + 826624);         // 3200000 B
    float* norm_src = (float*)(ws + 4026624);      // 200192 B
    float* norm_dst = (float*)(ws + 4226816);      // 200192 B
    int*   bsum     = (int*)(ws + 4427008);        // 1024 B
    float* aggbuf   = (float*)(ws + 4428032);      // 25.6 MB (also holds agg8 for layer 1)

    float* hbuf = out + (N_GRAPHS + N_GRAPHS * HD);  // h lives in d_out's h_co region

    hipMemsetAsync(ws, 0, ZERO_BYTES, stream);

    k_degrees<<<(N_EDGES + 255) / 256, 256, 0, stream>>>(src, dst, deg_in, deg_out);
    k_norms<<<(N_NODES + 255) / 256, 256, 0, stream>>>(deg_in, deg_out, gids,
                                                       norm_src, norm_dst, gcount);
    k_scan1<<<SCAN_NB, SCAN_B, 0, stream>>>(deg_in, off, bsum);
    k_scan2<<<1, SCAN_B, 0, stream>>>(bsum, off);
    k_scan3<<<SCAN_NB, SCAN_B, 0, stream>>>(off, bsum, cursor);
    k_scatter<<<(N_EDGES + 255) / 256, 256, 0, stream>>>(src, dst, cursor, csr);

    // layer 1: 8-dim features -> 128
    k_agg1<<<(N_NODES + 255) / 256, 256, 0, stream>>>(off, csr, deg_in, norm_src,
                                                      norm_dst, aggbuf);
    k_gemm1<<<N_NODES / 2, 256, 0, stream>>>(aggbuf, W1, b1, hbuf);

    // layers 2..5
    const float* Ws[4] = { W2, W3, W4, W5 };
    const float* bs[4] = { b2, b3, b4, b5 };
    for (int L = 0; L < 4; ++L) {
        k_agg<<<(N_NODES * 64 + 255) / 256, 256, 0, stream>>>(off, csr, norm_src,
                                                              norm_dst, hbuf, aggbuf);
        k_gemm<<<(N_NODES + TM - 1) / TM, 512, 0, stream>>>(aggbuf, Ws[L], bs[L], hbuf);
    }

    // pooling + head
    k_pool<<<N_NODES / POOL_CHUNK, 128, 0, stream>>>(hbuf, gids, gsum);
    k_head<<<N_GRAPHS, 64, 0, stream>>>(gsum, gcount, lw1, lb1, lw2, lb2, out);
}

// Round 4
// 626.562 us; speedup vs baseline: 1.6155x; 1.0609x over previous
//
#include <hip/hip_runtime.h>
#include <math.h>

#define N_NODES 50000
#define N_EDGES 800000
#define N_GRAPHS 50
#define HD 128
#define TM 64
#define LDA 68
#define POOL_CHUNK 125
#define SCAN_B 256
#define SCAN_NB ((N_NODES + SCAN_B - 1) / SCAN_B)   // 196

// ---------------- degree histograms ----------------
__global__ void k_degrees(const int* __restrict__ src, const int* __restrict__ dst,
                          int* deg_in, int* deg_out) {
    int e = blockIdx.x * blockDim.x + threadIdx.x;
    if (e < N_EDGES) {
        atomicAdd(&deg_in[dst[e]], 1);
        atomicAdd(&deg_out[src[e]], 1);
    }
}

// ---------------- norms + graph counts (LDS histogram) ----------------
__global__ void k_norms(const int* __restrict__ deg_in, const int* __restrict__ deg_out,
                        const int* __restrict__ gids,
                        float* norm_src, float* norm_dst, int* gcount) {
    __shared__ int hist[N_GRAPHS];
    int t = threadIdx.x;
    if (t < N_GRAPHS) hist[t] = 0;
    __syncthreads();
    int i = blockIdx.x * blockDim.x + t;
    if (i < N_NODES) {
        float di = (float)deg_in[i];
        float dq = (float)deg_out[i];
        norm_dst[i] = 1.0f / sqrtf(fmaxf(di, 1.0f));
        norm_src[i] = 1.0f / sqrtf(fmaxf(dq, 1.0f));
        atomicAdd(&hist[gids[i]], 1);
    }
    __syncthreads();
    if (t < N_GRAPHS && hist[t] != 0) atomicAdd(&gcount[t], hist[t]);
}

// ---------------- device-wide exclusive scan, 3 phases ----------------
__global__ void k_scan1(const int* __restrict__ deg_in, int* off, int* bsum) {
    __shared__ int sh[SCAN_B];
    int t = threadIdx.x;
    int i = blockIdx.x * SCAN_B + t;
    int v = (i < N_NODES) ? deg_in[i] : 0;
    sh[t] = v;
    __syncthreads();
    for (int o = 1; o < SCAN_B; o <<= 1) {
        int u = (t >= o) ? sh[t - o] : 0;
        __syncthreads();
        sh[t] += u;
        __syncthreads();
    }
    if (i < N_NODES) off[i] = sh[t] - v;          // local exclusive prefix
    if (t == SCAN_B - 1) bsum[blockIdx.x] = sh[t]; // block total
}

__global__ void k_scan2(int* bsum, int* off) {
    __shared__ int sh[SCAN_B];
    int t = threadIdx.x;
    int v = (t < SCAN_NB) ? bsum[t] : 0;
    sh[t] = v;
    __syncthreads();
    for (int o = 1; o < SCAN_B; o <<= 1) {
        int u = (t >= o) ? sh[t - o] : 0;
        __syncthreads();
        sh[t] += u;
        __syncthreads();
    }
    if (t < SCAN_NB) bsum[t] = sh[t] - v;          // exclusive block base
    if (t == SCAN_B - 1) off[N_NODES] = sh[t];     // total (= E)
}

__global__ void k_scan3(int* off, const int* __restrict__ bsum, int* cursor) {
    int b = blockIdx.x, t = threadIdx.x;
    int i = b * SCAN_B + t;
    if (i < N_NODES) {
        int o = off[i] + bsum[b];
        off[i] = o;
        cursor[i] = o;
    }
}

// ---------------- CSR scatter ----------------
__global__ void k_scatter(const int* __restrict__ src, const int* __restrict__ dst,
                          int* cursor, int* csr) {
    int e = blockIdx.x * blockDim.x + threadIdx.x;
    if (e < N_EDGES) {
        int p = atomicAdd(&cursor[dst[e]], 1);
        csr[p] = src[e];
    }
}

// ---------------- layer-1 aggregation (8-dim features from in-degree) ----------------
__global__ void k_agg1(const int* __restrict__ off, const int* __restrict__ csr,
                       const int* __restrict__ deg_in, const float* __restrict__ nsrc,
                       const float* __restrict__ ndst, float* __restrict__ agg8) {
    int i = blockIdx.x * blockDim.x + threadIdx.x;
    if (i >= N_NODES) return;
    int e0 = off[i], e1 = off[i + 1];
    float a0 = 0.f, a1 = 0.f, a2 = 0.f, a3 = 0.f;
    for (int e = e0; e < e1; ++e) {
        int s = csr[e];
        float ns = nsrc[s];
        float d = (float)deg_in[s];
        a0 += d * ns;
        a1 += (d > 3.0f) ? ns : 0.0f;
        a2 += (3.0f / d) * ns;
        a3 += (d > 4.0f) ? ns : 0.0f;
    }
    float nd = ndst[i];
    a0 *= nd; a1 *= nd; a2 *= nd; a3 *= nd;
    float* p = agg8 + (size_t)i * 8;
    p[0] = a0; p[1] = a1; p[2] = a2; p[3] = a3;
    p[4] = -a0; p[5] = -a1; p[6] = -a2; p[7] = -a3;
}

// ---------------- layer-1 GEMM 8 -> 128, fused bias+relu (+nsrc premult) -------------
__global__ void k_gemm1(const float* __restrict__ agg8, const float* __restrict__ W,
                        const float* __restrict__ b, const float* __restrict__ nsrc,
                        float* __restrict__ out) {
    __shared__ float Wsh[8 * 128];
    int t = threadIdx.x;
    for (int i = t; i < 1024; i += 256) Wsh[i] = W[i];
    __syncthreads();
    int row = blockIdx.x * 2 + (t >> 7);
    int j = t & 127;
    if (row >= N_NODES) return;
    const float* a = agg8 + (size_t)row * 8;
    float acc = b[j];
#pragma unroll
    for (int k = 0; k < 8; ++k) acc += a[k] * Wsh[k * 128 + j];
    out[(size_t)row * HD + j] = fmaxf(acc, 0.0f) * nsrc[row];
}

// ---------------- 128-dim aggregation: one wave per node, 4-deep MLP ----------------
// h is pre-multiplied by norm_src, so per edge: one float2 gather, no scalar chain.
__global__ void k_agg(const int* __restrict__ off, const int* __restrict__ csr,
                      const float* __restrict__ ndst,
                      const float* __restrict__ h, float* __restrict__ out) {
    int wid = (blockIdx.x * blockDim.x + threadIdx.x) >> 6;
    int lane = threadIdx.x & 63;
    if (wid >= N_NODES) return;
    int e0 = off[wid], e1 = off[wid + 1];
    float a0 = 0.f, a1 = 0.f;
    int e = e0;
    for (; e + 3 < e1; e += 4) {
        int s0 = csr[e], s1 = csr[e + 1], s2 = csr[e + 2], s3 = csr[e + 3];
        float2 v0 = *(const float2*)(h + (size_t)s0 * HD + lane * 2);
        float2 v1 = *(const float2*)(h + (size_t)s1 * HD + lane * 2);
        float2 v2 = *(const float2*)(h + (size_t)s2 * HD + lane * 2);
        float2 v3 = *(const float2*)(h + (size_t)s3 * HD + lane * 2);
        a0 += v0.x + v1.x + v2.x + v3.x;
        a1 += v0.y + v1.y + v2.y + v3.y;
    }
    for (; e < e1; ++e) {
        int s0 = csr[e];
        float2 v0 = *(const float2*)(h + (size_t)s0 * HD + lane * 2);
        a0 += v0.x; a1 += v0.y;
    }
    float nd = ndst[wid];
    float2 o; o.x = a0 * nd; o.y = a1 * nd;
    *(float2*)(out + (size_t)wid * HD + lane * 2) = o;
}

// ---------------- 128x128 GEMM, W + A^T in LDS, fused bias+relu (+opt nsrc) ---------
__global__ __launch_bounds__(512) void k_gemm(const float* __restrict__ A,
                                              const float* __restrict__ W,
                                              const float* __restrict__ b,
                                              const float* __restrict__ nsrc,
                                              int premult,
                                              float* __restrict__ out) {
    __shared__ float Wsh[128 * 128];      // 64 KB
    __shared__ float Ash[128 * LDA];      // ~34 KB, transposed A tile
    int t = threadIdx.x;
    const float4* W4 = (const float4*)W;
    float4* Wsh4 = (float4*)Wsh;
#pragma unroll
    for (int i = 0; i < 8; ++i) Wsh4[t + i * 512] = W4[t + i * 512];
    int row0 = blockIdx.x * TM;
#pragma unroll
    for (int i = 0; i < 4; ++i) {
        int idx = t + i * 512;      // 0..2047 float4 index over 64x128 tile
        int r = idx >> 5;           // row within tile
        int q = idx & 31;           // float4 column
        int row = row0 + r;
        if (row >= N_NODES) row = N_NODES - 1;
        float4 v = ((const float4*)(A + (size_t)row * HD))[q];
        Ash[(4 * q + 0) * LDA + r] = v.x;
        Ash[(4 * q + 1) * LDA + r] = v.y;
        Ash[(4 * q + 2) * LDA + r] = v.z;
        Ash[(4 * q + 3) * LDA + r] = v.w;
    }
    __syncthreads();
    int j0 = (t & 31) * 4;
    int r0 = (t >> 5) * 4;
    float4 bv = *(const float4*)(b + j0);
    float acc[4][4];
#pragma unroll
    for (int r = 0; r < 4; ++r) {
        acc[r][0] = bv.x; acc[r][1] = bv.y; acc[r][2] = bv.z; acc[r][3] = bv.w;
    }
#pragma unroll 4
    for (int k = 0; k < 128; ++k) {
        float4 w = *(const float4*)&Wsh[k * 128 + j0];
        float4 a = *(const float4*)&Ash[k * LDA + r0];
        acc[0][0] += a.x * w.x; acc[0][1] += a.x * w.y; acc[0][2] += a.x * w.z; acc[0][3] += a.x * w.w;
        acc[1][0] += a.y * w.x; acc[1][1] += a.y * w.y; acc[1][2] += a.y * w.z; acc[1][3] += a.y * w.w;
        acc[2][0] += a.z * w.x; acc[2][1] += a.z * w.y; acc[2][2] += a.z * w.z; acc[2][3] += a.z * w.w;
        acc[3][0] += a.w * w.x; acc[3][1] += a.w * w.y; acc[3][2] += a.w * w.z; acc[3][3] += a.w * w.w;
    }
#pragma unroll
    for (int r = 0; r < 4; ++r) {
        int row = row0 + r0 + r;
        if (row < N_NODES) {
            float sc = premult ? nsrc[row] : 1.0f;
            float* op = out + (size_t)row * HD + j0;
            float2 o01 = { fmaxf(acc[r][0], 0.f) * sc, fmaxf(acc[r][1], 0.f) * sc };
            float2 o23 = { fmaxf(acc[r][2], 0.f) * sc, fmaxf(acc[r][3], 0.f) * sc };
            *(float2*)op = o01;              // out may be only 8B-aligned (d_out+6450 floats)
            *(float2*)(op + 2) = o23;
        }
    }
}

// ---------------- mean-pool partials (125-node chunks, uniform graph id) ----------------
__global__ void k_pool(const float* __restrict__ hco, const int* __restrict__ gids,
                       float* gsum) {
    int f = threadIdx.x;                 // 128
    int n0 = blockIdx.x * POOL_CHUNK;
    int g = gids[n0];
    float s = 0.f;
    for (int i = 0; i < POOL_CHUNK; ++i)
        s += hco[(size_t)(n0 + i) * HD + f];
    atomicAdd(&gsum[g * HD + f], s);
}

// ---------------- head: graph_emb, MLP, sigmoid ----------------
__global__ void k_head(const float* __restrict__ gsum, const int* __restrict__ gcount,
                       const float* __restrict__ lw1, const float* __restrict__ lb1,
                       const float* __restrict__ lw2, const float* __restrict__ lb2,
                       float* __restrict__ dout) {
    __shared__ float ge[128];
    int g = blockIdx.x, j = threadIdx.x;  // 64 threads
    float cnt = (float)gcount[g];
    float g0 = gsum[g * HD + j] / cnt;
    float g1 = gsum[g * HD + 64 + j] / cnt;
    ge[j] = g0; ge[64 + j] = g1;
    dout[N_GRAPHS + g * HD + j] = g0;
    dout[N_GRAPHS + g * HD + 64 + j] = g1;
    __syncthreads();
    float acc = lb1[j];
#pragma unroll 4
    for (int k = 0; k < 128; ++k) acc += ge[k] * lw1[k * 64 + j];
    float he = fmaxf(acc, 0.f);
    float p = he * lw2[j];
#pragma unroll
    for (int o = 32; o > 0; o >>= 1) p += __shfl_down(p, o);
    if (j == 0) dout[g] = 1.0f / (1.0f + expf(-(p + lb2[0])));
}

extern "C" void kernel_launch(void* const* d_in, const int* in_sizes, int n_in,
                              void* d_out, int out_size, void* d_ws, size_t ws_size,
                              hipStream_t stream) {
    const int* src  = (const int*)d_in[0];
    const int* dst  = (const int*)d_in[1];
    const int* gids = (const int*)d_in[2];
    const float* W1 = (const float*)d_in[3];  const float* b1 = (const float*)d_in[4];
    const float* W2 = (const float*)d_in[5];  const float* b2 = (const float*)d_in[6];
    const float* W3 = (const float*)d_in[7];  const float* b3 = (const float*)d_in[8];
    const float* W4 = (const float*)d_in[9];  const float* b4 = (const float*)d_in[10];
    const float* W5 = (const float*)d_in[11]; const float* b5 = (const float*)d_in[12];
    const float* lw1 = (const float*)d_in[13]; const float* lb1 = (const float*)d_in[14];
    const float* lw2 = (const float*)d_in[15]; const float* lb2 = (const float*)d_in[16];
    float* out = (float*)d_out;

    char* ws = (char*)d_ws;
    // workspace layout (256B-aligned chunks)
    int*   deg_in   = (int*)(ws + 0);              // 200192 B
    int*   deg_out  = (int*)(ws + 200192);         // 200192 B
    int*   gcount   = (int*)(ws + 400384);         // 256 B
    float* gsum     = (float*)(ws + 400640);       // 25600 B
    const size_t ZERO_BYTES = 426240;              // everything above gets zeroed
    int*   off      = (int*)(ws + 426240);         // 200192 B
    int*   cursor   = (int*)(ws + 626432);         // 200192 B
    int*   csr      = (int*)(ws + 826624);         // 3200000 B
    float* norm_src = (float*)(ws + 4026624);      // 200192 B
    float* norm_dst = (float*)(ws + 4226816);      // 200192 B
    int*   bsum     = (int*)(ws + 4427008);        // 1024 B
    float* aggbuf   = (float*)(ws + 4428032);      // 25.6 MB (also holds agg8 for layer 1)

    float* hbuf = out + (N_GRAPHS + N_GRAPHS * HD);  // h lives in d_out's h_co region

    hipMemsetAsync(ws, 0, ZERO_BYTES, stream);

    k_degrees<<<(N_EDGES + 255) / 256, 256, 0, stream>>>(src, dst, deg_in, deg_out);
    k_norms<<<(N_NODES + 255) / 256, 256, 0, stream>>>(deg_in, deg_out, gids,
                                                       norm_src, norm_dst, gcount);
    k_scan1<<<SCAN_NB, SCAN_B, 0, stream>>>(deg_in, off, bsum);
    k_scan2<<<1, SCAN_B, 0, stream>>>(bsum, off);
    k_scan3<<<SCAN_NB, SCAN_B, 0, stream>>>(off, bsum, cursor);
    k_scatter<<<(N_EDGES + 255) / 256, 256, 0, stream>>>(src, dst, cursor, csr);

    // layer 1: 8-dim features -> 128 (output premultiplied by norm_src)
    k_agg1<<<(N_NODES + 255) / 256, 256, 0, stream>>>(off, csr, deg_in, norm_src,
                                                      norm_dst, aggbuf);
    k_gemm1<<<N_NODES / 2, 256, 0, stream>>>(aggbuf, W1, b1, norm_src, hbuf);

    // layers 2..5 (layers 2-4 premultiply norm_src into output; layer 5 raw = h_co)
    const float* Ws[4] = { W2, W3, W4, W5 };
    const float* bs[4] = { b2, b3, b4, b5 };
    for (int L = 0; L < 4; ++L) {
        k_agg<<<(N_NODES * 64 + 255) / 256, 256, 0, stream>>>(off, csr,
                                                              norm_dst, hbuf, aggbuf);
        k_gemm<<<(N_NODES + TM - 1) / TM, 512, 0, stream>>>(aggbuf, Ws[L], bs[L],
                                                            norm_src, (L < 3) ? 1 : 0,
                                                            hbuf);
    }

    // pooling + head
    k_pool<<<N_NODES / POOL_CHUNK, 128, 0, stream>>>(hbuf, gids, gsum);
    k_head<<<N_GRAPHS, 64, 0, stream>>>(gsum, gcount, lw1, lb1, lw2, lb2, out);
}

// Round 5
// 576.402 us; speedup vs baseline: 1.7561x; 1.0870x over previous
//
#include <hip/hip_runtime.h>
#include <math.h>

#define N_NODES 50000
#define N_EDGES 800000
#define N_GRAPHS 50
#define HD 128
#define TM 64
#define LDA 68
#define POOL_CHUNK 125
#define SCAN_B 256
#define SCAN_NB ((N_NODES + SCAN_B - 1) / SCAN_B)   // 196

// ---------------- degree histograms ----------------
__global__ void k_degrees(const int* __restrict__ src, const int* __restrict__ dst,
                          int* deg_in, int* deg_out) {
    int e = blockIdx.x * blockDim.x + threadIdx.x;
    if (e < N_EDGES) {
        atomicAdd(&deg_in[dst[e]], 1);
        atomicAdd(&deg_out[src[e]], 1);
    }
}

// ---------------- norms + graph counts + layer-1 edge payload ----------------
__global__ void k_norms(const int* __restrict__ deg_in, const int* __restrict__ deg_out,
                        const int* __restrict__ gids,
                        float* norm_src, float* norm_dst, int* gcount,
                        float4* __restrict__ feat4) {
    __shared__ int hist[N_GRAPHS];
    int t = threadIdx.x;
    if (t < N_GRAPHS) hist[t] = 0;
    __syncthreads();
    int i = blockIdx.x * blockDim.x + t;
    if (i < N_NODES) {
        float di = (float)deg_in[i];
        float dq = (float)deg_out[i];
        float nd = 1.0f / sqrtf(fmaxf(di, 1.0f));
        float ns = 1.0f / sqrtf(fmaxf(dq, 1.0f));
        norm_dst[i] = nd;
        norm_src[i] = ns;
        float4 f;
        f.x = di * ns;
        f.y = (di > 3.0f) ? ns : 0.0f;
        f.z = (3.0f / di) * ns;
        f.w = (di > 4.0f) ? ns : 0.0f;
        feat4[i] = f;
        atomicAdd(&hist[gids[i]], 1);
    }
    __syncthreads();
    if (t < N_GRAPHS && hist[t] != 0) atomicAdd(&gcount[t], hist[t]);
}

// ---------------- device-wide exclusive scan, 3 phases ----------------
__global__ void k_scan1(const int* __restrict__ deg_in, int* off, int* bsum) {
    __shared__ int sh[SCAN_B];
    int t = threadIdx.x;
    int i = blockIdx.x * SCAN_B + t;
    int v = (i < N_NODES) ? deg_in[i] : 0;
    sh[t] = v;
    __syncthreads();
    for (int o = 1; o < SCAN_B; o <<= 1) {
        int u = (t >= o) ? sh[t - o] : 0;
        __syncthreads();
        sh[t] += u;
        __syncthreads();
    }
    if (i < N_NODES) off[i] = sh[t] - v;          // local exclusive prefix
    if (t == SCAN_B - 1) bsum[blockIdx.x] = sh[t]; // block total
}

__global__ void k_scan2(int* bsum, int* off) {
    __shared__ int sh[SCAN_B];
    int t = threadIdx.x;
    int v = (t < SCAN_NB) ? bsum[t] : 0;
    sh[t] = v;
    __syncthreads();
    for (int o = 1; o < SCAN_B; o <<= 1) {
        int u = (t >= o) ? sh[t - o] : 0;
        __syncthreads();
        sh[t] += u;
        __syncthreads();
    }
    if (t < SCAN_NB) bsum[t] = sh[t] - v;          // exclusive block base
    if (t == SCAN_B - 1) off[N_NODES] = sh[t];     // total (= E)
}

__global__ void k_scan3(int* off, const int* __restrict__ bsum, int* cursor) {
    int b = blockIdx.x, t = threadIdx.x;
    int i = b * SCAN_B + t;
    if (i < N_NODES) {
        int o = off[i] + bsum[b];
        off[i] = o;
        cursor[i] = o;
    }
}

// ---------------- CSR scatter ----------------
__global__ void k_scatter(const int* __restrict__ src, const int* __restrict__ dst,
                          int* cursor, int* csr) {
    int e = blockIdx.x * blockDim.x + threadIdx.x;
    if (e < N_EDGES) {
        int p = atomicAdd(&cursor[dst[e]], 1);
        csr[p] = src[e];
    }
}

// ---------------- layer-1 aggregation: one float4 gather per edge ----------------
__global__ void k_agg1(const int* __restrict__ off, const int* __restrict__ csr,
                       const float4* __restrict__ feat4,
                       const float* __restrict__ ndst, float* __restrict__ agg8) {
    int i = blockIdx.x * blockDim.x + threadIdx.x;
    if (i >= N_NODES) return;
    int e0 = off[i], e1 = off[i + 1];
    float a0 = 0.f, a1 = 0.f, a2 = 0.f, a3 = 0.f;
    int e = e0;
    for (; e + 1 < e1; e += 2) {
        float4 f0 = feat4[csr[e]];
        float4 f1 = feat4[csr[e + 1]];
        a0 += f0.x + f1.x; a1 += f0.y + f1.y;
        a2 += f0.z + f1.z; a3 += f0.w + f1.w;
    }
    if (e < e1) {
        float4 f0 = feat4[csr[e]];
        a0 += f0.x; a1 += f0.y; a2 += f0.z; a3 += f0.w;
    }
    float nd = ndst[i];
    a0 *= nd; a1 *= nd; a2 *= nd; a3 *= nd;
    float4* p = (float4*)(agg8 + (size_t)i * 8);
    float4 hi = { a0, a1, a2, a3 };
    float4 lo = { -a0, -a1, -a2, -a3 };
    p[0] = hi;
    p[1] = lo;
}

// ---------------- layer-1 GEMM 8 -> 128, fused bias+relu (+nsrc premult) -------------
__global__ void k_gemm1(const float* __restrict__ agg8, const float* __restrict__ W,
                        const float* __restrict__ b, const float* __restrict__ nsrc,
                        float* __restrict__ out) {
    __shared__ float Wsh[8 * 128];
    int t = threadIdx.x;
    for (int i = t; i < 1024; i += 256) Wsh[i] = W[i];
    __syncthreads();
    int row = blockIdx.x * 2 + (t >> 7);
    int j = t & 127;
    if (row >= N_NODES) return;
    const float* a = agg8 + (size_t)row * 8;
    float acc = b[j];
#pragma unroll
    for (int k = 0; k < 8; ++k) acc += a[k] * Wsh[k * 128 + j];
    out[(size_t)row * HD + j] = fmaxf(acc, 0.0f) * nsrc[row];
}

// ---------------- 128-dim aggregation, float4 half-wave-per-edge ----------------
// h rows must be 16B-aligned. Lanes 0-31 handle even edge slots, 32-63 odd.
__global__ void k_agg4(const int* __restrict__ off, const int* __restrict__ csr,
                       const float* __restrict__ ndst,
                       const float* __restrict__ h, float* __restrict__ out) {
    int wid = (blockIdx.x * blockDim.x + threadIdx.x) >> 6;
    int lane = threadIdx.x & 63;
    if (wid >= N_NODES) return;
    int half = lane >> 5;
    int q = lane & 31;
    int e0 = off[wid], e1 = off[wid + 1];
    float4 a = { 0.f, 0.f, 0.f, 0.f };
    int e = e0 + half;
    for (; e + 2 < e1; e += 4) {
        int s0 = csr[e], s1 = csr[e + 2];
        float4 v0 = *(const float4*)(h + (size_t)s0 * HD + q * 4);
        float4 v1 = *(const float4*)(h + (size_t)s1 * HD + q * 4);
        a.x += v0.x + v1.x; a.y += v0.y + v1.y;
        a.z += v0.z + v1.z; a.w += v0.w + v1.w;
    }
    if (e < e1) {
        int s0 = csr[e];
        float4 v0 = *(const float4*)(h + (size_t)s0 * HD + q * 4);
        a.x += v0.x; a.y += v0.y; a.z += v0.z; a.w += v0.w;
    }
    // combine the two halves (lane l <-> l+32 hold the same feature range)
    a.x += __shfl_xor(a.x, 32);
    a.y += __shfl_xor(a.y, 32);
    a.z += __shfl_xor(a.z, 32);
    a.w += __shfl_xor(a.w, 32);
    if (half == 0) {
        float nd = ndst[wid];
        a.x *= nd; a.y *= nd; a.z *= nd; a.w *= nd;
        *(float4*)(out + (size_t)wid * HD + q * 4) = a;
    }
}

// ---------------- fallback float2 aggregation (h only 8B-aligned) ----------------
__global__ void k_agg2(const int* __restrict__ off, const int* __restrict__ csr,
                       const float* __restrict__ ndst,
                       const float* __restrict__ h, float* __restrict__ out) {
    int wid = (blockIdx.x * blockDim.x + threadIdx.x) >> 6;
    int lane = threadIdx.x & 63;
    if (wid >= N_NODES) return;
    int e0 = off[wid], e1 = off[wid + 1];
    float a0 = 0.f, a1 = 0.f;
    int e = e0;
    for (; e + 3 < e1; e += 4) {
        int s0 = csr[e], s1 = csr[e + 1], s2 = csr[e + 2], s3 = csr[e + 3];
        float2 v0 = *(const float2*)(h + (size_t)s0 * HD + lane * 2);
        float2 v1 = *(const float2*)(h + (size_t)s1 * HD + lane * 2);
        float2 v2 = *(const float2*)(h + (size_t)s2 * HD + lane * 2);
        float2 v3 = *(const float2*)(h + (size_t)s3 * HD + lane * 2);
        a0 += v0.x + v1.x + v2.x + v3.x;
        a1 += v0.y + v1.y + v2.y + v3.y;
    }
    for (; e < e1; ++e) {
        int s0 = csr[e];
        float2 v0 = *(const float2*)(h + (size_t)s0 * HD + lane * 2);
        a0 += v0.x; a1 += v0.y;
    }
    float nd = ndst[wid];
    float2 o; o.x = a0 * nd; o.y = a1 * nd;
    *(float2*)(out + (size_t)wid * HD + lane * 2) = o;
}

// ---------------- 128x128 GEMM, W + A^T in LDS, fused bias+relu (+opt nsrc) ---------
__global__ __launch_bounds__(512) void k_gemm(const float* __restrict__ A,
                                              const float* __restrict__ W,
                                              const float* __restrict__ b,
                                              const float* __restrict__ nsrc,
                                              int premult,
                                              float* __restrict__ out) {
    __shared__ float Wsh[128 * 128];      // 64 KB
    __shared__ float Ash[128 * LDA];      // ~34 KB, transposed A tile
    int t = threadIdx.x;
    const float4* W4 = (const float4*)W;
    float4* Wsh4 = (float4*)Wsh;
#pragma unroll
    for (int i = 0; i < 8; ++i) Wsh4[t + i * 512] = W4[t + i * 512];
    int row0 = blockIdx.x * TM;
#pragma unroll
    for (int i = 0; i < 4; ++i) {
        int idx = t + i * 512;      // 0..2047 float4 index over 64x128 tile
        int r = idx >> 5;           // row within tile
        int q = idx & 31;           // float4 column
        int row = row0 + r;
        if (row >= N_NODES) row = N_NODES - 1;
        float4 v = ((const float4*)(A + (size_t)row * HD))[q];
        Ash[(4 * q + 0) * LDA + r] = v.x;
        Ash[(4 * q + 1) * LDA + r] = v.y;
        Ash[(4 * q + 2) * LDA + r] = v.z;
        Ash[(4 * q + 3) * LDA + r] = v.w;
    }
    __syncthreads();
    int j0 = (t & 31) * 4;
    int r0 = (t >> 5) * 4;
    float4 bv = *(const float4*)(b + j0);
    float acc[4][4];
#pragma unroll
    for (int r = 0; r < 4; ++r) {
        acc[r][0] = bv.x; acc[r][1] = bv.y; acc[r][2] = bv.z; acc[r][3] = bv.w;
    }
#pragma unroll 4
    for (int k = 0; k < 128; ++k) {
        float4 w = *(const float4*)&Wsh[k * 128 + j0];
        float4 a = *(const float4*)&Ash[k * LDA + r0];
        acc[0][0] += a.x * w.x; acc[0][1] += a.x * w.y; acc[0][2] += a.x * w.z; acc[0][3] += a.x * w.w;
        acc[1][0] += a.y * w.x; acc[1][1] += a.y * w.y; acc[1][2] += a.y * w.z; acc[1][3] += a.y * w.w;
        acc[2][0] += a.z * w.x; acc[2][1] += a.z * w.y; acc[2][2] += a.z * w.z; acc[2][3] += a.z * w.w;
        acc[3][0] += a.w * w.x; acc[3][1] += a.w * w.y; acc[3][2] += a.w * w.z; acc[3][3] += a.w * w.w;
    }
#pragma unroll
    for (int r = 0; r < 4; ++r) {
        int row = row0 + r0 + r;
        if (row < N_NODES) {
            float sc = premult ? nsrc[row] : 1.0f;
            float* op = out + (size_t)row * HD + j0;
            float2 o01 = { fmaxf(acc[r][0], 0.f) * sc, fmaxf(acc[r][1], 0.f) * sc };
            float2 o23 = { fmaxf(acc[r][2], 0.f) * sc, fmaxf(acc[r][3], 0.f) * sc };
            *(float2*)op = o01;              // dest may be only 8B-aligned (d_out+6450 floats)
            *(float2*)(op + 2) = o23;
        }
    }
}

// ---------------- mean-pool partials (125-node chunks, uniform graph id) ----------------
__global__ void k_pool(const float* __restrict__ hco, const int* __restrict__ gids,
                       float* gsum) {
    int f = threadIdx.x;                 // 128
    int n0 = blockIdx.x * POOL_CHUNK;
    int g = gids[n0];
    float s = 0.f;
    for (int i = 0; i < POOL_CHUNK; ++i)
        s += hco[(size_t)(n0 + i) * HD + f];
    atomicAdd(&gsum[g * HD + f], s);
}

// ---------------- head: graph_emb, MLP, sigmoid ----------------
__global__ void k_head(const float* __restrict__ gsum, const int* __restrict__ gcount,
                       const float* __restrict__ lw1, const float* __restrict__ lb1,
                       const float* __restrict__ lw2, const float* __restrict__ lb2,
                       float* __restrict__ dout) {
    __shared__ float ge[128];
    int g = blockIdx.x, j = threadIdx.x;  // 64 threads
    float cnt = (float)gcount[g];
    float g0 = gsum[g * HD + j] / cnt;
    float g1 = gsum[g * HD + 64 + j] / cnt;
    ge[j] = g0; ge[64 + j] = g1;
    dout[N_GRAPHS + g * HD + j] = g0;
    dout[N_GRAPHS + g * HD + 64 + j] = g1;
    __syncthreads();
    float acc = lb1[j];
#pragma unroll 4
    for (int k = 0; k < 128; ++k) acc += ge[k] * lw1[k * 64 + j];
    float he = fmaxf(acc, 0.f);
    float p = he * lw2[j];
#pragma unroll
    for (int o = 32; o > 0; o >>= 1) p += __shfl_down(p, o);
    if (j == 0) dout[g] = 1.0f / (1.0f + expf(-(p + lb2[0])));
}

extern "C" void kernel_launch(void* const* d_in, const int* in_sizes, int n_in,
                              void* d_out, int out_size, void* d_ws, size_t ws_size,
                              hipStream_t stream) {
    const int* src  = (const int*)d_in[0];
    const int* dst  = (const int*)d_in[1];
    const int* gids = (const int*)d_in[2];
    const float* W1 = (const float*)d_in[3];  const float* b1 = (const float*)d_in[4];
    const float* W2 = (const float*)d_in[5];  const float* b2 = (const float*)d_in[6];
    const float* W3 = (const float*)d_in[7];  const float* b3 = (const float*)d_in[8];
    const float* W4 = (const float*)d_in[9];  const float* b4 = (const float*)d_in[10];
    const float* W5 = (const float*)d_in[11]; const float* b5 = (const float*)d_in[12];
    const float* lw1 = (const float*)d_in[13]; const float* lb1 = (const float*)d_in[14];
    const float* lw2 = (const float*)d_in[15]; const float* lb2 = (const float*)d_in[16];
    float* out = (float*)d_out;

    char* ws = (char*)d_ws;
    // workspace layout (256B-aligned chunks)
    int*    deg_in   = (int*)(ws + 0);              // 200192 B
    int*    deg_out  = (int*)(ws + 200192);         // 200192 B
    int*    gcount   = (int*)(ws + 400384);         // 256 B
    float*  gsum     = (float*)(ws + 400640);       // 25600 B
    const size_t ZERO_BYTES = 426240;               // everything above gets zeroed
    int*    off      = (int*)(ws + 426240);         // 200192 B
    int*    cursor   = (int*)(ws + 626432);         // 200192 B
    int*    csr      = (int*)(ws + 826624);         // 3200000 B
    float*  norm_src = (float*)(ws + 4026624);      // 200192 B
    float*  norm_dst = (float*)(ws + 4226816);      // 200192 B
    int*    bsum     = (int*)(ws + 4427008);        // 1024 B
    float4* feat4    = (float4*)(ws + 4428032);     // 800000 B (pad to 800256)
    float*  aggbuf   = (float*)(ws + 5228288);      // 25.6 MB
    float*  hws      = (float*)(ws + 30828288);     // 25.6 MB (16B-aligned h rows)
    const size_t WS_NEEDED = 30828288 + 25600000;   // ~53.8 MB

    float* hco = out + (N_GRAPHS + N_GRAPHS * HD);  // layer-5 output = h_co region
    bool aligned = (ws_size >= WS_NEEDED);
    float* hbuf = aligned ? hws : hco;              // inter-layer h storage

    hipMemsetAsync(ws, 0, ZERO_BYTES, stream);

    k_degrees<<<(N_EDGES + 255) / 256, 256, 0, stream>>>(src, dst, deg_in, deg_out);
    k_norms<<<(N_NODES + 255) / 256, 256, 0, stream>>>(deg_in, deg_out, gids,
                                                       norm_src, norm_dst, gcount, feat4);
    k_scan1<<<SCAN_NB, SCAN_B, 0, stream>>>(deg_in, off, bsum);
    k_scan2<<<1, SCAN_B, 0, stream>>>(bsum, off);
    k_scan3<<<SCAN_NB, SCAN_B, 0, stream>>>(off, bsum, cursor);
    k_scatter<<<(N_EDGES + 255) / 256, 256, 0, stream>>>(src, dst, cursor, csr);

    // layer 1: 8-dim features -> 128 (output premultiplied by norm_src)
    k_agg1<<<(N_NODES + 255) / 256, 256, 0, stream>>>(off, csr, feat4, norm_dst, aggbuf);
    k_gemm1<<<N_NODES / 2, 256, 0, stream>>>(aggbuf, W1, b1, norm_src, hbuf);

    // layers 2..5 (layers 2-4 premultiply norm_src into output; layer 5 raw = h_co)
    const float* Ws[4] = { W2, W3, W4, W5 };
    const float* bs[4] = { b2, b3, b4, b5 };
    for (int L = 0; L < 4; ++L) {
        if (aligned)
            k_agg4<<<(N_NODES * 64 + 255) / 256, 256, 0, stream>>>(off, csr,
                                                                   norm_dst, hbuf, aggbuf);
        else
            k_agg2<<<(N_NODES * 64 + 255) / 256, 256, 0, stream>>>(off, csr,
                                                                   norm_dst, hbuf, aggbuf);
        float* gout = (L < 3) ? hbuf : hco;  // layer-5 output goes to d_out
        k_gemm<<<(N_NODES + TM - 1) / TM, 512, 0, stream>>>(aggbuf, Ws[L], bs[L],
                                                            norm_src, (L < 3) ? 1 : 0,
                                                            gout);
    }

    // pooling + head
    k_pool<<<N_NODES / POOL_CHUNK, 128, 0, stream>>>(hco, gids, gsum);
    k_head<<<N_GRAPHS, 64, 0, stream>>>(gsum, gcount, lw1, lb1, lw2, lb2, out);
}

// Round 6
// 540.519 us; speedup vs baseline: 1.8726x; 1.0664x over previous
//
#include <hip/hip_runtime.h>
#include <math.h>

#define N_NODES 50000
#define N_EDGES 800000
#define N_GRAPHS 50
#define HD 128
#define TM 64
#define LDA 68
#define POOL_CHUNK 125
#define SCAN_B 256
#define SCAN_NB ((N_NODES + SCAN_B - 1) / SCAN_B)   // 196
#define NB_H 128
#define CH_H (N_EDGES / NB_H)                        // 6250
#define NBIN2 (N_NODES / 2)                          // 25000 packed dwords

// ---------------- degree histograms: LDS uint16-packed partials ----------------
__global__ __launch_bounds__(256) void k_hist(const int* __restrict__ src,
                                              const int* __restrict__ dst,
                                              unsigned* __restrict__ part_in,
                                              unsigned* __restrict__ part_out) {
    __shared__ unsigned cnt[NBIN2];      // 100 KB: 50000 uint16 counts
    int t = threadIdx.x, b = blockIdx.x;
    int e0 = b * CH_H;
    for (int j = t; j < NBIN2; j += 256) cnt[j] = 0;
    __syncthreads();
    for (int e = e0 + t; e < e0 + CH_H; e += 256) {
        int i = dst[e];
        atomicAdd(&cnt[i >> 1], 1u << ((i & 1) * 16));
    }
    __syncthreads();
    for (int j = t; j < NBIN2; j += 256) part_in[b * NBIN2 + j] = cnt[j];
    __syncthreads();
    for (int j = t; j < NBIN2; j += 256) cnt[j] = 0;
    __syncthreads();
    for (int e = e0 + t; e < e0 + CH_H; e += 256) {
        int i = src[e];
        atomicAdd(&cnt[i >> 1], 1u << ((i & 1) * 16));
    }
    __syncthreads();
    for (int j = t; j < NBIN2; j += 256) part_out[b * NBIN2 + j] = cnt[j];
}

__global__ void k_dreduce(const unsigned* __restrict__ part_in,
                          const unsigned* __restrict__ part_out,
                          int* __restrict__ deg_in, int* __restrict__ deg_out) {
    int j = blockIdx.x * blockDim.x + threadIdx.x;
    if (j >= NBIN2) return;
    unsigned ilo = 0, ihi = 0, olo = 0, ohi = 0;
#pragma unroll 4
    for (int b = 0; b < NB_H; ++b) {
        unsigned pi = part_in[b * NBIN2 + j];
        unsigned po = part_out[b * NBIN2 + j];
        ilo += pi & 0xFFFFu; ihi += pi >> 16;
        olo += po & 0xFFFFu; ohi += po >> 16;
    }
    ((int2*)deg_in)[j] = make_int2((int)ilo, (int)ihi);
    ((int2*)deg_out)[j] = make_int2((int)olo, (int)ohi);
}

// ---------------- norms + graph counts + layer-1 edge payload ----------------
__global__ void k_norms(const int* __restrict__ deg_in, const int* __restrict__ deg_out,
                        const int* __restrict__ gids,
                        float* norm_src, float* norm_dst, int* gcount,
                        float4* __restrict__ feat4) {
    __shared__ int hist[N_GRAPHS];
    int t = threadIdx.x;
    if (t < N_GRAPHS) hist[t] = 0;
    __syncthreads();
    int i = blockIdx.x * blockDim.x + t;
    if (i < N_NODES) {
        float di = (float)deg_in[i];
        float dq = (float)deg_out[i];
        float nd = 1.0f / sqrtf(fmaxf(di, 1.0f));
        float ns = 1.0f / sqrtf(fmaxf(dq, 1.0f));
        norm_dst[i] = nd;
        norm_src[i] = ns;
        float4 f;
        f.x = di * ns;
        f.y = (di > 3.0f) ? ns : 0.0f;
        f.z = (3.0f / di) * ns;
        f.w = (di > 4.0f) ? ns : 0.0f;
        feat4[i] = f;
        atomicAdd(&hist[gids[i]], 1);
    }
    __syncthreads();
    if (t < N_GRAPHS && hist[t] != 0) atomicAdd(&gcount[t], hist[t]);
}

// ---------------- device-wide exclusive scan, 3 phases ----------------
__global__ void k_scan1(const int* __restrict__ deg_in, int* off, int* bsum) {
    __shared__ int sh[SCAN_B];
    int t = threadIdx.x;
    int i = blockIdx.x * SCAN_B + t;
    int v = (i < N_NODES) ? deg_in[i] : 0;
    sh[t] = v;
    __syncthreads();
    for (int o = 1; o < SCAN_B; o <<= 1) {
        int u = (t >= o) ? sh[t - o] : 0;
        __syncthreads();
        sh[t] += u;
        __syncthreads();
    }
    if (i < N_NODES) off[i] = sh[t] - v;          // local exclusive prefix
    if (t == SCAN_B - 1) bsum[blockIdx.x] = sh[t]; // block total
}

__global__ void k_scan2(int* bsum, int* off) {
    __shared__ int sh[SCAN_B];
    int t = threadIdx.x;
    int v = (t < SCAN_NB) ? bsum[t] : 0;
    sh[t] = v;
    __syncthreads();
    for (int o = 1; o < SCAN_B; o <<= 1) {
        int u = (t >= o) ? sh[t - o] : 0;
        __syncthreads();
        sh[t] += u;
        __syncthreads();
    }
    if (t < SCAN_NB) bsum[t] = sh[t] - v;          // exclusive block base
    if (t == SCAN_B - 1) off[N_NODES] = sh[t];     // total (= E)
}

__global__ void k_scan3(int* off, const int* __restrict__ bsum, int* cursor) {
    int b = blockIdx.x, t = threadIdx.x;
    int i = b * SCAN_B + t;
    if (i < N_NODES) {
        int o = off[i] + bsum[b];
        off[i] = o;
        cursor[i] = o;
    }
}

// ---------------- CSR scatter ----------------
__global__ void k_scatter(const int* __restrict__ src, const int* __restrict__ dst,
                          int* cursor, int* csr) {
    int e = blockIdx.x * blockDim.x + threadIdx.x;
    if (e < N_EDGES) {
        int p = atomicAdd(&cursor[dst[e]], 1);
        csr[p] = src[e];
    }
}

// ---------------- layer-1 aggregation: one float4 gather per edge ----------------
__global__ void k_agg1(const int* __restrict__ off, const int* __restrict__ csr,
                       const float4* __restrict__ feat4,
                       const float* __restrict__ ndst, float* __restrict__ agg8) {
    int i = blockIdx.x * blockDim.x + threadIdx.x;
    if (i >= N_NODES) return;
    int e0 = off[i], e1 = off[i + 1];
    float a0 = 0.f, a1 = 0.f, a2 = 0.f, a3 = 0.f;
    int e = e0;
    for (; e + 1 < e1; e += 2) {
        float4 f0 = feat4[csr[e]];
        float4 f1 = feat4[csr[e + 1]];
        a0 += f0.x + f1.x; a1 += f0.y + f1.y;
        a2 += f0.z + f1.z; a3 += f0.w + f1.w;
    }
    if (e < e1) {
        float4 f0 = feat4[csr[e]];
        a0 += f0.x; a1 += f0.y; a2 += f0.z; a3 += f0.w;
    }
    float nd = ndst[i];
    a0 *= nd; a1 *= nd; a2 *= nd; a3 *= nd;
    float4* p = (float4*)(agg8 + (size_t)i * 8);
    float4 hi = { a0, a1, a2, a3 };
    float4 lo = { -a0, -a1, -a2, -a3 };
    p[0] = hi;
    p[1] = lo;
}

// ---------------- layer-1 GEMM 8 -> 128, fused bias+relu (+nsrc premult) -------------
__global__ void k_gemm1(const float* __restrict__ agg8, const float* __restrict__ W,
                        const float* __restrict__ b, const float* __restrict__ nsrc,
                        float* __restrict__ out) {
    __shared__ float Wsh[8 * 128];
    int t = threadIdx.x;
    for (int i = t; i < 1024; i += 256) Wsh[i] = W[i];
    __syncthreads();
    int row = blockIdx.x * 2 + (t >> 7);
    int j = t & 127;
    if (row >= N_NODES) return;
    const float* a = agg8 + (size_t)row * 8;
    float acc = b[j];
#pragma unroll
    for (int k = 0; k < 8; ++k) acc += a[k] * Wsh[k * 128 + j];
    out[(size_t)row * HD + j] = fmaxf(acc, 0.0f) * nsrc[row];
}

// ---------------- 128-dim aggregation, float4 half-wave-per-edge ----------------
__global__ void k_agg4(const int* __restrict__ off, const int* __restrict__ csr,
                       const float* __restrict__ ndst,
                       const float* __restrict__ h, float* __restrict__ out) {
    int wid = (blockIdx.x * blockDim.x + threadIdx.x) >> 6;
    int lane = threadIdx.x & 63;
    if (wid >= N_NODES) return;
    int half = lane >> 5;
    int q = lane & 31;
    int e0 = off[wid], e1 = off[wid + 1];
    float4 a = { 0.f, 0.f, 0.f, 0.f };
    int e = e0 + half;
    for (; e + 2 < e1; e += 4) {
        int s0 = csr[e], s1 = csr[e + 2];
        float4 v0 = *(const float4*)(h + (size_t)s0 * HD + q * 4);
        float4 v1 = *(const float4*)(h + (size_t)s1 * HD + q * 4);
        a.x += v0.x + v1.x; a.y += v0.y + v1.y;
        a.z += v0.z + v1.z; a.w += v0.w + v1.w;
    }
    if (e < e1) {
        int s0 = csr[e];
        float4 v0 = *(const float4*)(h + (size_t)s0 * HD + q * 4);
        a.x += v0.x; a.y += v0.y; a.z += v0.z; a.w += v0.w;
    }
    a.x += __shfl_xor(a.x, 32);
    a.y += __shfl_xor(a.y, 32);
    a.z += __shfl_xor(a.z, 32);
    a.w += __shfl_xor(a.w, 32);
    if (half == 0) {
        float nd = ndst[wid];
        a.x *= nd; a.y *= nd; a.z *= nd; a.w *= nd;
        *(float4*)(out + (size_t)wid * HD + q * 4) = a;
    }
}

// ---------------- fallback float2 aggregation (h only 8B-aligned) ----------------
__global__ void k_agg2(const int* __restrict__ off, const int* __restrict__ csr,
                       const float* __restrict__ ndst,
                       const float* __restrict__ h, float* __restrict__ out) {
    int wid = (blockIdx.x * blockDim.x + threadIdx.x) >> 6;
    int lane = threadIdx.x & 63;
    if (wid >= N_NODES) return;
    int e0 = off[wid], e1 = off[wid + 1];
    float a0 = 0.f, a1 = 0.f;
    int e = e0;
    for (; e + 3 < e1; e += 4) {
        int s0 = csr[e], s1 = csr[e + 1], s2 = csr[e + 2], s3 = csr[e + 3];
        float2 v0 = *(const float2*)(h + (size_t)s0 * HD + lane * 2);
        float2 v1 = *(const float2*)(h + (size_t)s1 * HD + lane * 2);
        float2 v2 = *(const float2*)(h + (size_t)s2 * HD + lane * 2);
        float2 v3 = *(const float2*)(h + (size_t)s3 * HD + lane * 2);
        a0 += v0.x + v1.x + v2.x + v3.x;
        a1 += v0.y + v1.y + v2.y + v3.y;
    }
    for (; e < e1; ++e) {
        int s0 = csr[e];
        float2 v0 = *(const float2*)(h + (size_t)s0 * HD + lane * 2);
        a0 += v0.x; a1 += v0.y;
    }
    float nd = ndst[wid];
    float2 o; o.x = a0 * nd; o.y = a1 * nd;
    *(float2*)(out + (size_t)wid * HD + lane * 2) = o;
}

// ---------------- 128x128 GEMM, W + A^T in LDS, fused bias+relu (+opt nsrc) ---------
__global__ __launch_bounds__(512) void k_gemm(const float* __restrict__ A,
                                              const float* __restrict__ W,
                                              const float* __restrict__ b,
                                              const float* __restrict__ nsrc,
                                              int premult,
                                              float* __restrict__ out) {
    __shared__ float Wsh[128 * 128];      // 64 KB
    __shared__ float Ash[128 * LDA];      // ~34 KB, transposed A tile
    int t = threadIdx.x;
    const float4* W4 = (const float4*)W;
    float4* Wsh4 = (float4*)Wsh;
#pragma unroll
    for (int i = 0; i < 8; ++i) Wsh4[t + i * 512] = W4[t + i * 512];
    int row0 = blockIdx.x * TM;
#pragma unroll
    for (int i = 0; i < 4; ++i) {
        int idx = t + i * 512;      // 0..2047 float4 index over 64x128 tile
        int r = idx >> 5;           // row within tile
        int q = idx & 31;           // float4 column
        int row = row0 + r;
        if (row >= N_NODES) row = N_NODES - 1;
        float4 v = ((const float4*)(A + (size_t)row * HD))[q];
        Ash[(4 * q + 0) * LDA + r] = v.x;
        Ash[(4 * q + 1) * LDA + r] = v.y;
        Ash[(4 * q + 2) * LDA + r] = v.z;
        Ash[(4 * q + 3) * LDA + r] = v.w;
    }
    __syncthreads();
    int j0 = (t & 31) * 4;
    int r0 = (t >> 5) * 4;
    float4 bv = *(const float4*)(b + j0);
    float acc[4][4];
#pragma unroll
    for (int r = 0; r < 4; ++r) {
        acc[r][0] = bv.x; acc[r][1] = bv.y; acc[r][2] = bv.z; acc[r][3] = bv.w;
    }
#pragma unroll 4
    for (int k = 0; k < 128; ++k) {
        float4 w = *(const float4*)&Wsh[k * 128 + j0];
        float4 a = *(const float4*)&Ash[k * LDA + r0];
        acc[0][0] += a.x * w.x; acc[0][1] += a.x * w.y; acc[0][2] += a.x * w.z; acc[0][3] += a.x * w.w;
        acc[1][0] += a.y * w.x; acc[1][1] += a.y * w.y; acc[1][2] += a.y * w.z; acc[1][3] += a.y * w.w;
        acc[2][0] += a.z * w.x; acc[2][1] += a.z * w.y; acc[2][2] += a.z * w.z; acc[2][3] += a.z * w.w;
        acc[3][0] += a.w * w.x; acc[3][1] += a.w * w.y; acc[3][2] += a.w * w.z; acc[3][3] += a.w * w.w;
    }
#pragma unroll
    for (int r = 0; r < 4; ++r) {
        int row = row0 + r0 + r;
        if (row < N_NODES) {
            float sc = premult ? nsrc[row] : 1.0f;
            float* op = out + (size_t)row * HD + j0;
            float2 o01 = { fmaxf(acc[r][0], 0.f) * sc, fmaxf(acc[r][1], 0.f) * sc };
            float2 o23 = { fmaxf(acc[r][2], 0.f) * sc, fmaxf(acc[r][3], 0.f) * sc };
            *(float2*)op = o01;              // dest may be only 8B-aligned (d_out+6450 floats)
            *(float2*)(op + 2) = o23;
        }
    }
}

// ---------------- mean-pool partials (125-node chunks, uniform graph id) ----------------
__global__ void k_pool(const float* __restrict__ hco, const int* __restrict__ gids,
                       float* gsum) {
    int f = threadIdx.x;                 // 128
    int n0 = blockIdx.x * POOL_CHUNK;
    int g = gids[n0];
    float s = 0.f;
    for (int i = 0; i < POOL_CHUNK; ++i)
        s += hco[(size_t)(n0 + i) * HD + f];
    atomicAdd(&gsum[g * HD + f], s);
}

// ---------------- head: graph_emb, MLP, sigmoid ----------------
__global__ void k_head(const float* __restrict__ gsum, const int* __restrict__ gcount,
                       const float* __restrict__ lw1, const float* __restrict__ lb1,
                       const float* __restrict__ lw2, const float* __restrict__ lb2,
                       float* __restrict__ dout) {
    __shared__ float ge[128];
    int g = blockIdx.x, j = threadIdx.x;  // 64 threads
    float cnt = (float)gcount[g];
    float g0 = gsum[g * HD + j] / cnt;
    float g1 = gsum[g * HD + 64 + j] / cnt;
    ge[j] = g0; ge[64 + j] = g1;
    dout[N_GRAPHS + g * HD + j] = g0;
    dout[N_GRAPHS + g * HD + 64 + j] = g1;
    __syncthreads();
    float acc = lb1[j];
#pragma unroll 4
    for (int k = 0; k < 128; ++k) acc += ge[k] * lw1[k * 64 + j];
    float he = fmaxf(acc, 0.f);
    float p = he * lw2[j];
#pragma unroll
    for (int o = 32; o > 0; o >>= 1) p += __shfl_down(p, o);
    if (j == 0) dout[g] = 1.0f / (1.0f + expf(-(p + lb2[0])));
}

extern "C" void kernel_launch(void* const* d_in, const int* in_sizes, int n_in,
                              void* d_out, int out_size, void* d_ws, size_t ws_size,
                              hipStream_t stream) {
    const int* src  = (const int*)d_in[0];
    const int* dst  = (const int*)d_in[1];
    const int* gids = (const int*)d_in[2];
    const float* W1 = (const float*)d_in[3];  const float* b1 = (const float*)d_in[4];
    const float* W2 = (const float*)d_in[5];  const float* b2 = (const float*)d_in[6];
    const float* W3 = (const float*)d_in[7];  const float* b3 = (const float*)d_in[8];
    const float* W4 = (const float*)d_in[9];  const float* b4 = (const float*)d_in[10];
    const float* W5 = (const float*)d_in[11]; const float* b5 = (const float*)d_in[12];
    const float* lw1 = (const float*)d_in[13]; const float* lb1 = (const float*)d_in[14];
    const float* lw2 = (const float*)d_in[15]; const float* lb2 = (const float*)d_in[16];
    float* out = (float*)d_out;

    char* ws = (char*)d_ws;
    // workspace layout (256B-aligned chunks); gcount+gsum first so the memset is tiny
    int*    gcount   = (int*)(ws + 0);              // 256 B
    float*  gsum     = (float*)(ws + 256);          // 25600 B
    const size_t ZERO_BYTES = 25856;                // only gcount+gsum need zeroing
    int*    deg_in   = (int*)(ws + 26112);          // 200192 B
    int*    deg_out  = (int*)(ws + 226304);         // 200192 B
    int*    off      = (int*)(ws + 426496);         // 200192 B
    int*    cursor   = (int*)(ws + 626688);         // 200192 B
    int*    csr      = (int*)(ws + 826880);         // 3200000 B
    float*  norm_src = (float*)(ws + 4026880);      // 200192 B
    float*  norm_dst = (float*)(ws + 4227072);      // 200192 B
    int*    bsum     = (int*)(ws + 4427264);        // 1024 B
    float4* feat4    = (float4*)(ws + 4428288);     // 800256 B
    float*  aggbuf   = (float*)(ws + 5228544);      // 25.6 MB (also hist partials)
    float*  hws      = (float*)(ws + 30828544);     // 25.6 MB (16B-aligned h rows)
    const size_t WS_NEEDED = 30828544 + 25600000;

    // histogram partials alias aggbuf (dead until k_agg1)
    unsigned* part_in  = (unsigned*)aggbuf;                  // 12.8 MB
    unsigned* part_out = (unsigned*)aggbuf + NB_H * NBIN2;   // 12.8 MB

    float* hco = out + (N_GRAPHS + N_GRAPHS * HD);  // layer-5 output = h_co region
    bool aligned = (ws_size >= WS_NEEDED);
    float* hbuf = aligned ? hws : hco;              // inter-layer h storage

    hipMemsetAsync(ws, 0, ZERO_BYTES, stream);

    k_hist<<<NB_H, 256, 0, stream>>>(src, dst, part_in, part_out);
    k_dreduce<<<(NBIN2 + 255) / 256, 256, 0, stream>>>(part_in, part_out,
                                                       deg_in, deg_out);
    k_norms<<<(N_NODES + 255) / 256, 256, 0, stream>>>(deg_in, deg_out, gids,
                                                       norm_src, norm_dst, gcount, feat4);
    k_scan1<<<SCAN_NB, SCAN_B, 0, stream>>>(deg_in, off, bsum);
    k_scan2<<<1, SCAN_B, 0, stream>>>(bsum, off);
    k_scan3<<<SCAN_NB, SCAN_B, 0, stream>>>(off, bsum, cursor);
    k_scatter<<<(N_EDGES + 255) / 256, 256, 0, stream>>>(src, dst, cursor, csr);

    // layer 1: 8-dim features -> 128 (output premultiplied by norm_src)
    k_agg1<<<(N_NODES + 255) / 256, 256, 0, stream>>>(off, csr, feat4, norm_dst, aggbuf);
    k_gemm1<<<N_NODES / 2, 256, 0, stream>>>(aggbuf, W1, b1, norm_src, hbuf);

    // layers 2..5 (layers 2-4 premultiply norm_src into output; layer 5 raw = h_co)
    const float* Ws[4] = { W2, W3, W4, W5 };
    const float* bs[4] = { b2, b3, b4, b5 };
    for (int L = 0; L < 4; ++L) {
        if (aligned)
            k_agg4<<<(N_NODES * 64 + 255) / 256, 256, 0, stream>>>(off, csr,
                                                                   norm_dst, hbuf, aggbuf);
        else
            k_agg2<<<(N_NODES * 64 + 255) / 256, 256, 0, stream>>>(off, csr,
                                                                   norm_dst, hbuf, aggbuf);
        float* gout = (L < 3) ? hbuf : hco;  // layer-5 output goes to d_out
        k_gemm<<<(N_NODES + TM - 1) / TM, 512, 0, stream>>>(aggbuf, Ws[L], bs[L],
                                                            norm_src, (L < 3) ? 1 : 0,
                                                            gout);
    }

    // pooling + head
    k_pool<<<N_NODES / POOL_CHUNK, 128, 0, stream>>>(hco, gids, gsum);
    k_head<<<N_GRAPHS, 64, 0, stream>>>(gsum, gcount, lw1, lb1, lw2, lb2, out);
}

// Round 7
// 519.731 us; speedup vs baseline: 1.9475x; 1.0400x over previous
//
#include <hip/hip_runtime.h>
#include <math.h>

#define N_NODES 50000
#define N_EDGES 800000
#define N_GRAPHS 50
#define HD 128
#define TM 64
#define LDA 68
#define POOL_CHUNK 125
#define SCAN_B 256
#define SCAN_NB ((N_NODES + SCAN_B - 1) / SCAN_B)   // 196
#define NB_H 128
#define CH_H (N_EDGES / NB_H)                        // 6250
#define NBIN2 (N_NODES / 2)                          // 25000 packed dwords

// ---------------- degree histograms: LDS uint16-packed partials ----------------
__global__ __launch_bounds__(256) void k_hist(const int* __restrict__ src,
                                              const int* __restrict__ dst,
                                              unsigned* __restrict__ part_in,
                                              unsigned* __restrict__ part_out) {
    __shared__ unsigned cnt[NBIN2];      // 100 KB: 50000 uint16 counts
    int t = threadIdx.x, b = blockIdx.x;
    int e0 = b * CH_H;
    for (int j = t; j < NBIN2; j += 256) cnt[j] = 0;
    __syncthreads();
    for (int e = e0 + t; e < e0 + CH_H; e += 256) {
        int i = dst[e];
        atomicAdd(&cnt[i >> 1], 1u << ((i & 1) * 16));
    }
    __syncthreads();
    for (int j = t; j < NBIN2; j += 256) part_in[b * NBIN2 + j] = cnt[j];
    __syncthreads();
    for (int j = t; j < NBIN2; j += 256) cnt[j] = 0;
    __syncthreads();
    for (int e = e0 + t; e < e0 + CH_H; e += 256) {
        int i = src[e];
        atomicAdd(&cnt[i >> 1], 1u << ((i & 1) * 16));
    }
    __syncthreads();
    for (int j = t; j < NBIN2; j += 256) part_out[b * NBIN2 + j] = cnt[j];
}

// reduce partials to degrees; ALSO convert part_in to per-block exclusive
// prefix bases (packed uint16, in-place) for the atomic-free scatter.
__global__ void k_dreduce(unsigned* __restrict__ part_in,
                          const unsigned* __restrict__ part_out,
                          int* __restrict__ deg_in, int* __restrict__ deg_out) {
    int j = blockIdx.x * blockDim.x + threadIdx.x;
    if (j >= NBIN2) return;
    unsigned run_i = 0, run_o = 0;       // packed halves; per-half sums < 2^16
    for (int b = 0; b < NB_H; ++b) {
        unsigned pi = part_in[b * NBIN2 + j];
        unsigned po = part_out[b * NBIN2 + j];
        part_in[b * NBIN2 + j] = run_i;  // exclusive prefix over blocks
        run_i += pi;
        run_o += po;
    }
    ((int2*)deg_in)[j] = make_int2((int)(run_i & 0xFFFFu), (int)(run_i >> 16));
    ((int2*)deg_out)[j] = make_int2((int)(run_o & 0xFFFFu), (int)(run_o >> 16));
}

// ---------------- norms + graph counts + layer-1 edge payload ----------------
__global__ void k_norms(const int* __restrict__ deg_in, const int* __restrict__ deg_out,
                        const int* __restrict__ gids,
                        float* norm_src, float* norm_dst, int* gcount,
                        float4* __restrict__ feat4) {
    __shared__ int hist[N_GRAPHS];
    int t = threadIdx.x;
    if (t < N_GRAPHS) hist[t] = 0;
    __syncthreads();
    int i = blockIdx.x * blockDim.x + t;
    if (i < N_NODES) {
        float di = (float)deg_in[i];
        float dq = (float)deg_out[i];
        float nd = 1.0f / sqrtf(fmaxf(di, 1.0f));
        float ns = 1.0f / sqrtf(fmaxf(dq, 1.0f));
        norm_dst[i] = nd;
        norm_src[i] = ns;
        float4 f;
        f.x = di * ns;
        f.y = (di > 3.0f) ? ns : 0.0f;
        f.z = (3.0f / di) * ns;
        f.w = (di > 4.0f) ? ns : 0.0f;
        feat4[i] = f;
        atomicAdd(&hist[gids[i]], 1);
    }
    __syncthreads();
    if (t < N_GRAPHS && hist[t] != 0) atomicAdd(&gcount[t], hist[t]);
}

// ---------------- device-wide exclusive scan, 3 phases ----------------
__global__ void k_scan1(const int* __restrict__ deg_in, int* off, int* bsum) {
    __shared__ int sh[SCAN_B];
    int t = threadIdx.x;
    int i = blockIdx.x * SCAN_B + t;
    int v = (i < N_NODES) ? deg_in[i] : 0;
    sh[t] = v;
    __syncthreads();
    for (int o = 1; o < SCAN_B; o <<= 1) {
        int u = (t >= o) ? sh[t - o] : 0;
        __syncthreads();
        sh[t] += u;
        __syncthreads();
    }
    if (i < N_NODES) off[i] = sh[t] - v;          // local exclusive prefix
    if (t == SCAN_B - 1) bsum[blockIdx.x] = sh[t]; // block total
}

__global__ void k_scan2(int* bsum, int* off) {
    __shared__ int sh[SCAN_B];
    int t = threadIdx.x;
    int v = (t < SCAN_NB) ? bsum[t] : 0;
    sh[t] = v;
    __syncthreads();
    for (int o = 1; o < SCAN_B; o <<= 1) {
        int u = (t >= o) ? sh[t - o] : 0;
        __syncthreads();
        sh[t] += u;
        __syncthreads();
    }
    if (t < SCAN_NB) bsum[t] = sh[t] - v;          // exclusive block base
    if (t == SCAN_B - 1) off[N_NODES] = sh[t];     // total (= E)
}

__global__ void k_scan3(int* off, const int* __restrict__ bsum) {
    int b = blockIdx.x, t = threadIdx.x;
    int i = b * SCAN_B + t;
    if (i < N_NODES) off[i] += bsum[b];
}

// ---------------- CSR scatter, atomic-free (LDS packed rank cursors) ----------------
__global__ __launch_bounds__(256) void k_scatter2(const int* __restrict__ src,
                                                  const int* __restrict__ dst,
                                                  const int* __restrict__ off,
                                                  const unsigned* __restrict__ part_in,
                                                  int* __restrict__ csr) {
    __shared__ unsigned cur[NBIN2];      // packed {prefix+rank} per node
    int t = threadIdx.x, b = blockIdx.x;
    const unsigned* base = part_in + (size_t)b * NBIN2;
    for (int j = t; j < NBIN2; j += 256) cur[j] = base[j];
    __syncthreads();
    int e0 = b * CH_H;
    for (int e = e0 + t; e < e0 + CH_H; e += 256) {
        int d = dst[e];
        int sh = (d & 1) * 16;
        unsigned old = atomicAdd(&cur[d >> 1], 1u << sh);
        int rank = (int)((old >> sh) & 0xFFFFu);
        csr[off[d] + rank] = src[e];
    }
}

// ---------------- layer-1 aggregation: one float4 gather per edge ----------------
__global__ void k_agg1(const int* __restrict__ off, const int* __restrict__ csr,
                       const float4* __restrict__ feat4,
                       const float* __restrict__ ndst, float* __restrict__ agg8) {
    int i = blockIdx.x * blockDim.x + threadIdx.x;
    if (i >= N_NODES) return;
    int e0 = off[i], e1 = off[i + 1];
    float a0 = 0.f, a1 = 0.f, a2 = 0.f, a3 = 0.f;
    int e = e0;
    for (; e + 1 < e1; e += 2) {
        float4 f0 = feat4[csr[e]];
        float4 f1 = feat4[csr[e + 1]];
        a0 += f0.x + f1.x; a1 += f0.y + f1.y;
        a2 += f0.z + f1.z; a3 += f0.w + f1.w;
    }
    if (e < e1) {
        float4 f0 = feat4[csr[e]];
        a0 += f0.x; a1 += f0.y; a2 += f0.z; a3 += f0.w;
    }
    float nd = ndst[i];
    a0 *= nd; a1 *= nd; a2 *= nd; a3 *= nd;
    float4* p = (float4*)(agg8 + (size_t)i * 8);
    float4 hi = { a0, a1, a2, a3 };
    float4 lo = { -a0, -a1, -a2, -a3 };
    p[0] = hi;
    p[1] = lo;
}

// ---------------- layer-1 GEMM 8 -> 128, fused bias+relu (+nsrc premult) -------------
__global__ void k_gemm1(const float* __restrict__ agg8, const float* __restrict__ W,
                        const float* __restrict__ b, const float* __restrict__ nsrc,
                        float* __restrict__ out) {
    __shared__ float Wsh[8 * 128];
    int t = threadIdx.x;
    for (int i = t; i < 1024; i += 256) Wsh[i] = W[i];
    __syncthreads();
    int row = blockIdx.x * 2 + (t >> 7);
    int j = t & 127;
    if (row >= N_NODES) return;
    const float* a = agg8 + (size_t)row * 8;
    float acc = b[j];
#pragma unroll
    for (int k = 0; k < 8; ++k) acc += a[k] * Wsh[k * 128 + j];
    out[(size_t)row * HD + j] = fmaxf(acc, 0.0f) * nsrc[row];
}

// ---------------- 128-dim aggregation, float4 half-wave-per-edge, 4-deep MLP --------
__global__ __launch_bounds__(256) void k_agg4(const int* __restrict__ off,
                                              const int* __restrict__ csr,
                                              const float* __restrict__ ndst,
                                              const float* __restrict__ h,
                                              float* __restrict__ out) {
    int wid = (blockIdx.x * blockDim.x + threadIdx.x) >> 6;
    int lane = threadIdx.x & 63;
    if (wid >= N_NODES) return;
    int half = lane >> 5;
    int q = lane & 31;
    int e0 = off[wid], e1 = off[wid + 1];
    float4 a = { 0.f, 0.f, 0.f, 0.f };
    int e = e0 + half;
    for (; e + 6 < e1; e += 8) {       // 4 edges per half, 8 per wave-iter
        int s0 = csr[e], s1 = csr[e + 2], s2 = csr[e + 4], s3 = csr[e + 6];
        float4 v0 = *(const float4*)(h + (size_t)s0 * HD + q * 4);
        float4 v1 = *(const float4*)(h + (size_t)s1 * HD + q * 4);
        float4 v2 = *(const float4*)(h + (size_t)s2 * HD + q * 4);
        float4 v3 = *(const float4*)(h + (size_t)s3 * HD + q * 4);
        a.x += v0.x + v1.x + v2.x + v3.x;
        a.y += v0.y + v1.y + v2.y + v3.y;
        a.z += v0.z + v1.z + v2.z + v3.z;
        a.w += v0.w + v1.w + v2.w + v3.w;
    }
    for (; e < e1; e += 2) {
        int s0 = csr[e];
        float4 v0 = *(const float4*)(h + (size_t)s0 * HD + q * 4);
        a.x += v0.x; a.y += v0.y; a.z += v0.z; a.w += v0.w;
    }
    a.x += __shfl_xor(a.x, 32);
    a.y += __shfl_xor(a.y, 32);
    a.z += __shfl_xor(a.z, 32);
    a.w += __shfl_xor(a.w, 32);
    if (half == 0) {
        float nd = ndst[wid];
        a.x *= nd; a.y *= nd; a.z *= nd; a.w *= nd;
        *(float4*)(out + (size_t)wid * HD + q * 4) = a;
    }
}

// ---------------- fallback float2 aggregation (h only 8B-aligned) ----------------
__global__ void k_agg2(const int* __restrict__ off, const int* __restrict__ csr,
                       const float* __restrict__ ndst,
                       const float* __restrict__ h, float* __restrict__ out) {
    int wid = (blockIdx.x * blockDim.x + threadIdx.x) >> 6;
    int lane = threadIdx.x & 63;
    if (wid >= N_NODES) return;
    int e0 = off[wid], e1 = off[wid + 1];
    float a0 = 0.f, a1 = 0.f;
    int e = e0;
    for (; e + 3 < e1; e += 4) {
        int s0 = csr[e], s1 = csr[e + 1], s2 = csr[e + 2], s3 = csr[e + 3];
        float2 v0 = *(const float2*)(h + (size_t)s0 * HD + lane * 2);
        float2 v1 = *(const float2*)(h + (size_t)s1 * HD + lane * 2);
        float2 v2 = *(const float2*)(h + (size_t)s2 * HD + lane * 2);
        float2 v3 = *(const float2*)(h + (size_t)s3 * HD + lane * 2);
        a0 += v0.x + v1.x + v2.x + v3.x;
        a1 += v0.y + v1.y + v2.y + v3.y;
    }
    for (; e < e1; ++e) {
        int s0 = csr[e];
        float2 v0 = *(const float2*)(h + (size_t)s0 * HD + lane * 2);
        a0 += v0.x; a1 += v0.y;
    }
    float nd = ndst[wid];
    float2 o; o.x = a0 * nd; o.y = a1 * nd;
    *(float2*)(out + (size_t)wid * HD + lane * 2) = o;
}

// ---------------- 128x128 GEMM, W + A^T in LDS, fused bias+relu (+opt nsrc) ---------
__global__ __launch_bounds__(512) void k_gemm(const float* __restrict__ A,
                                              const float* __restrict__ W,
                                              const float* __restrict__ b,
                                              const float* __restrict__ nsrc,
                                              int premult,
                                              float* __restrict__ out) {
    __shared__ float Wsh[128 * 128];      // 64 KB
    __shared__ float Ash[128 * LDA];      // ~34 KB, transposed A tile
    int t = threadIdx.x;
    const float4* W4 = (const float4*)W;
    float4* Wsh4 = (float4*)Wsh;
#pragma unroll
    for (int i = 0; i < 8; ++i) Wsh4[t + i * 512] = W4[t + i * 512];
    int row0 = blockIdx.x * TM;
#pragma unroll
    for (int i = 0; i < 4; ++i) {
        int idx = t + i * 512;      // 0..2047 float4 index over 64x128 tile
        int r = idx >> 5;           // row within tile
        int q = idx & 31;           // float4 column
        int row = row0 + r;
        if (row >= N_NODES) row = N_NODES - 1;
        float4 v = ((const float4*)(A + (size_t)row * HD))[q];
        Ash[(4 * q + 0) * LDA + r] = v.x;
        Ash[(4 * q + 1) * LDA + r] = v.y;
        Ash[(4 * q + 2) * LDA + r] = v.z;
        Ash[(4 * q + 3) * LDA + r] = v.w;
    }
    __syncthreads();
    int j0 = (t & 31) * 4;
    int r0 = (t >> 5) * 4;
    float4 bv = *(const float4*)(b + j0);
    float acc[4][4];
#pragma unroll
    for (int r = 0; r < 4; ++r) {
        acc[r][0] = bv.x; acc[r][1] = bv.y; acc[r][2] = bv.z; acc[r][3] = bv.w;
    }
#pragma unroll 4
    for (int k = 0; k < 128; ++k) {
        float4 w = *(const float4*)&Wsh[k * 128 + j0];
        float4 a = *(const float4*)&Ash[k * LDA + r0];
        acc[0][0] += a.x * w.x; acc[0][1] += a.x * w.y; acc[0][2] += a.x * w.z; acc[0][3] += a.x * w.w;
        acc[1][0] += a.y * w.x; acc[1][1] += a.y * w.y; acc[1][2] += a.y * w.z; acc[1][3] += a.y * w.w;
        acc[2][0] += a.z * w.x; acc[2][1] += a.z * w.y; acc[2][2] += a.z * w.z; acc[2][3] += a.z * w.w;
        acc[3][0] += a.w * w.x; acc[3][1] += a.w * w.y; acc[3][2] += a.w * w.z; acc[3][3] += a.w * w.w;
    }
#pragma unroll
    for (int r = 0; r < 4; ++r) {
        int row = row0 + r0 + r;
        if (row < N_NODES) {
            float sc = premult ? nsrc[row] : 1.0f;
            float* op = out + (size_t)row * HD + j0;
            float2 o01 = { fmaxf(acc[r][0], 0.f) * sc, fmaxf(acc[r][1], 0.f) * sc };
            float2 o23 = { fmaxf(acc[r][2], 0.f) * sc, fmaxf(acc[r][3], 0.f) * sc };
            *(float2*)op = o01;              // dest may be only 8B-aligned (d_out+6450 floats)
            *(float2*)(op + 2) = o23;
        }
    }
}

// ---------------- mean-pool partials (125-node chunks, uniform graph id) ----------------
__global__ void k_pool(const float* __restrict__ hco, const int* __restrict__ gids,
                       float* gsum) {
    int f = threadIdx.x;                 // 128
    int n0 = blockIdx.x * POOL_CHUNK;
    int g = gids[n0];
    float s = 0.f;
    for (int i = 0; i < POOL_CHUNK; ++i)
        s += hco[(size_t)(n0 + i) * HD + f];
    atomicAdd(&gsum[g * HD + f], s);
}

// ---------------- head: graph_emb, MLP, sigmoid ----------------
__global__ void k_head(const float* __restrict__ gsum, const int* __restrict__ gcount,
                       const float* __restrict__ lw1, const float* __restrict__ lb1,
                       const float* __restrict__ lw2, const float* __restrict__ lb2,
                       float* __restrict__ dout) {
    __shared__ float ge[128];
    int g = blockIdx.x, j = threadIdx.x;  // 64 threads
    float cnt = (float)gcount[g];
    float g0 = gsum[g * HD + j] / cnt;
    float g1 = gsum[g * HD + 64 + j] / cnt;
    ge[j] = g0; ge[64 + j] = g1;
    dout[N_GRAPHS + g * HD + j] = g0;
    dout[N_GRAPHS + g * HD + 64 + j] = g1;
    __syncthreads();
    float acc = lb1[j];
#pragma unroll 4
    for (int k = 0; k < 128; ++k) acc += ge[k] * lw1[k * 64 + j];
    float he = fmaxf(acc, 0.f);
    float p = he * lw2[j];
#pragma unroll
    for (int o = 32; o > 0; o >>= 1) p += __shfl_down(p, o);
    if (j == 0) dout[g] = 1.0f / (1.0f + expf(-(p + lb2[0])));
}

extern "C" void kernel_launch(void* const* d_in, const int* in_sizes, int n_in,
                              void* d_out, int out_size, void* d_ws, size_t ws_size,
                              hipStream_t stream) {
    const int* src  = (const int*)d_in[0];
    const int* dst  = (const int*)d_in[1];
    const int* gids = (const int*)d_in[2];
    const float* W1 = (const float*)d_in[3];  const float* b1 = (const float*)d_in[4];
    const float* W2 = (const float*)d_in[5];  const float* b2 = (const float*)d_in[6];
    const float* W3 = (const float*)d_in[7];  const float* b3 = (const float*)d_in[8];
    const float* W4 = (const float*)d_in[9];  const float* b4 = (const float*)d_in[10];
    const float* W5 = (const float*)d_in[11]; const float* b5 = (const float*)d_in[12];
    const float* lw1 = (const float*)d_in[13]; const float* lb1 = (const float*)d_in[14];
    const float* lw2 = (const float*)d_in[15]; const float* lb2 = (const float*)d_in[16];
    float* out = (float*)d_out;

    char* ws = (char*)d_ws;
    // workspace layout (256B-aligned chunks); gcount+gsum first so the memset is tiny
    int*    gcount   = (int*)(ws + 0);              // 256 B
    float*  gsum     = (float*)(ws + 256);          // 25600 B
    const size_t ZERO_BYTES = 25856;                // only gcount+gsum need zeroing
    int*    deg_in   = (int*)(ws + 26112);          // 200192 B
    int*    deg_out  = (int*)(ws + 226304);         // 200192 B
    int*    off      = (int*)(ws + 426496);         // 200192 B
    int*    csr      = (int*)(ws + 826880);         // 3200000 B
    float*  norm_src = (float*)(ws + 4026880);      // 200192 B
    float*  norm_dst = (float*)(ws + 4227072);      // 200192 B
    int*    bsum     = (int*)(ws + 4427264);        // 1024 B
    float4* feat4    = (float4*)(ws + 4428288);     // 800256 B
    float*  aggbuf   = (float*)(ws + 5228544);      // 25.6 MB (also hist partials)
    float*  hws      = (float*)(ws + 30828544);     // 25.6 MB (16B-aligned h rows)
    const size_t WS_NEEDED = 30828544 + 25600000;

    // histogram partials alias aggbuf (dead until k_agg1)
    unsigned* part_in  = (unsigned*)aggbuf;                  // 12.8 MB
    unsigned* part_out = (unsigned*)aggbuf + NB_H * NBIN2;   // 12.8 MB

    float* hco = out + (N_GRAPHS + N_GRAPHS * HD);  // layer-5 output = h_co region
    bool aligned = (ws_size >= WS_NEEDED);
    float* hbuf = aligned ? hws : hco;              // inter-layer h storage

    hipMemsetAsync(ws, 0, ZERO_BYTES, stream);

    k_hist<<<NB_H, 256, 0, stream>>>(src, dst, part_in, part_out);
    k_dreduce<<<(NBIN2 + 255) / 256, 256, 0, stream>>>(part_in, part_out,
                                                       deg_in, deg_out);
    k_norms<<<(N_NODES + 255) / 256, 256, 0, stream>>>(deg_in, deg_out, gids,
                                                       norm_src, norm_dst, gcount, feat4);
    k_scan1<<<SCAN_NB, SCAN_B, 0, stream>>>(deg_in, off, bsum);
    k_scan2<<<1, SCAN_B, 0, stream>>>(bsum, off);
    k_scan3<<<SCAN_NB, SCAN_B, 0, stream>>>(off, bsum);
    k_scatter2<<<NB_H, 256, 0, stream>>>(src, dst, off, part_in, csr);

    // layer 1: 8-dim features -> 128 (output premultiplied by norm_src)
    k_agg1<<<(N_NODES + 255) / 256, 256, 0, stream>>>(off, csr, feat4, norm_dst, aggbuf);
    k_gemm1<<<N_NODES / 2, 256, 0, stream>>>(aggbuf, W1, b1, norm_src, hbuf);

    // layers 2..5 (layers 2-4 premultiply norm_src into output; layer 5 raw = h_co)
    const float* Ws[4] = { W2, W3, W4, W5 };
    const float* bs[4] = { b2, b3, b4, b5 };
    for (int L = 0; L < 4; ++L) {
        if (aligned)
            k_agg4<<<(N_NODES * 64 + 255) / 256, 256, 0, stream>>>(off, csr,
                                                                   norm_dst, hbuf, aggbuf);
        else
            k_agg2<<<(N_NODES * 64 + 255) / 256, 256, 0, stream>>>(off, csr,
                                                                   norm_dst, hbuf, aggbuf);
        float* gout = (L < 3) ? hbuf : hco;  // layer-5 output goes to d_out
        k_gemm<<<(N_NODES + TM - 1) / TM, 512, 0, stream>>>(aggbuf, Ws[L], bs[L],
                                                            norm_src, (L < 3) ? 1 : 0,
                                                            gout);
    }

    // pooling + head
    k_pool<<<N_NODES / POOL_CHUNK, 128, 0, stream>>>(hco, gids, gsum);
    k_head<<<N_GRAPHS, 64, 0, stream>>>(gsum, gcount, lw1, lb1, lw2, lb2, out);
}